// Round 15
// baseline (2059.675 us; speedup 1.0000x reference)
//
#include <hip/hip_runtime.h>
#include <math.h>

#define NN 512
#define TSEQ 12
#define BB 64

typedef unsigned short u16;
typedef short s16x4 __attribute__((ext_vector_type(4)));
typedef short s16x8 __attribute__((ext_vector_type(8)));
typedef float f32x4 __attribute__((ext_vector_type(4)));

__device__ __forceinline__ float b2f(u16 h) { return __uint_as_float(((unsigned)h) << 16); }
__device__ __forceinline__ u16 f2b(float f) {
    unsigned u = __float_as_uint(f);
    return (u16)((u + 0x7FFFu + ((u >> 16) & 1u)) >> 16);
}

// ---------------- workspace layout (bytes) ----------------
constexpr size_t SZP    = (size_t)512 * 4096 * 2;   // one state plane (4 MB)
constexpr size_t B_ADJ  = 0;                        // u16 [512][512] adjacency (0/1, exact bf16)
constexpr size_t B_DD   = B_ADJ + 524288;           // f32 [512] degrees
constexpr size_t B_NRM  = B_DD + 2048;
constexpr size_t B_LMAX = B_NRM + 2048;             // f32 [64]
constexpr size_t B_XSH  = B_LMAX + 256;             // u16 [512][768] x hi
constexpr size_t B_XSL  = B_XSH + 786432;
constexpr size_t B_TXH  = B_XSL + 786432;
constexpr size_t B_TXL  = B_TXH + 786432;
constexpr size_t B_ST   = B_TXL + 786432;           // 12 planes
constexpr size_t B_RBUF = B_ST + 12 * SZP;          // f32 [512][64][64]
constexpr size_t B_G0TH = B_RBUF + 8388608;         // u16 [512][128][128]
constexpr size_t B_G0TL = B_G0TH + 16777216;
constexpr size_t B_U0TH = B_G0TL + 16777216;        // u16 [512][64][128]
constexpr size_t B_U0TL = B_U0TH + 8388608;
constexpr size_t B_G1TH = B_U0TL + 8388608;         // u16 [512][128][256]
constexpr size_t B_G1TL = B_G1TH + 33554432;
constexpr size_t B_U1TH = B_G1TL + 33554432;        // u16 [512][64][256]
constexpr size_t B_U1TL = B_U1TH + 16777216;
constexpr size_t B_BG0  = B_U1TL + 16777216;        // f32 [512][128]
constexpr size_t B_BU0  = B_BG0 + 262144;           // f32 [512][64]
constexpr size_t B_BG1  = B_BU0 + 131072;
constexpr size_t B_BU1  = B_BG1 + 262144;
constexpr size_t B_G0X  = B_BU1 + 131072;           // f32 [512][2][128]
constexpr size_t B_U0X  = B_G0X + 524288;           // f32 [512][2][64]
constexpr size_t WS_BYTES = B_U0X + 262144;         // ~205 MiB

// ---------------- setup kernels ----------------

__global__ void k_marker(float* out, float v) { out[threadIdx.x] = v; }

__global__ void k_norm(const float* __restrict__ E, float* __restrict__ nrm) {
    int n = blockIdx.x * blockDim.x + threadIdx.x;
    if (n < NN) {
        float s = 0.f;
        #pragma unroll
        for (int q = 0; q < 10; ++q) { float e = E[n * 10 + q]; s += e * e; }
        nrm[n] = sqrtf(s);
    }
}

__global__ __launch_bounds__(256) void k_adj(const float* __restrict__ E, const float* __restrict__ gn,
                                             const float* __restrict__ nrm, u16* __restrict__ adjb,
                                             float* __restrict__ dd) {
    __shared__ float En[10];
    __shared__ float red[256];
    int n = blockIdx.x, tid = threadIdx.x;
    if (tid < 10) En[tid] = E[n * 10 + tid];
    __syncthreads();
    float nn = nrm[n];
    float cnt = 0.f;
    for (int m = tid; m < NN; m += 256) {
        float dot = 0.f;
        #pragma unroll
        for (int q = 0; q < 10; ++q) dot += En[q] * E[m * 10 + q];
        float lg = dot / (nn * nrm[m]);
        lg = (lg + 1.f) * 0.5f;
        float g0 = gn[((size_t)n * NN + m) * 2 + 0];
        float g1 = gn[((size_t)n * NN + m) * 2 + 1];
        bool a = ((lg + g0) >= (1.f - lg + g1) && (m != n));
        adjb[(size_t)n * NN + m] = a ? 0x3F80 : 0;
        cnt += a ? 1.f : 0.f;
    }
    red[tid] = cnt;
    __syncthreads();
    for (int s = 128; s > 0; s >>= 1) { if (tid < s) red[tid] += red[tid + s]; __syncthreads(); }
    if (tid == 0) dd[n] = red[0];
}

__global__ void k_dmax(const float* __restrict__ dd, float* __restrict__ lmax) {
    __shared__ float red[512];
    int t = threadIdx.x;
    red[t] = dd[t];
    __syncthreads();
    for (int s = 256; s > 0; s >>= 1) { if (t < s) red[t] = fmaxf(red[t], red[t + s]); __syncthreads(); }
    if (t == 0) lmax[0] = red[0] + (red[0] > 0.f ? 1.f : 0.f);
}

__global__ __launch_bounds__(256) void k_xs_bf(const float* __restrict__ gts, u16* __restrict__ xh,
                                               u16* __restrict__ xl) {
    int idx = blockIdx.x * 256 + threadIdx.x;
    if (idx >= NN * TSEQ * BB) return;
    int n = idx / (TSEQ * BB);
    int rem = idx - n * (TSEQ * BB);
    int t = rem >> 6, b = rem & 63;
    float v = gts[((size_t)b * NN + n) * TSEQ + t];
    u16 hb = f2b(v);
    xh[idx] = hb;
    xl[idx] = f2b(v - b2f(hb));
}

// ---------------- embed v2 (round-14): Wp slice in LDS, amortized over 16 nodes ----------------
template <int K2, int O, bool SHIFT>
__global__ __launch_bounds__(256) void k_embed2(const float* __restrict__ E, const float* __restrict__ Wp,
                                                u16* __restrict__ oh, u16* __restrict__ ol) {
    constexpr int KR = SHIFT ? 130 : K2;
    __shared__ float WpL[10][32][33];
    __shared__ float eL[16][10];
    const int nc = blockIdx.x, kc = blockIdx.y, oc = blockIdx.z;
    const int tid = threadIdx.x;
    const int rb = kc * 32 + (SHIFT ? (kc >= 2 ? 2 : 1) : 0);
    const int ocol = oc * 32;
    const int n0 = nc * 16;

    for (int el = tid; el < 10 * 32 * 32; el += 256) {
        int d = el >> 10;
        int rem = el & 1023;
        int k = rem >> 5, o = rem & 31;
        WpL[d][k][o] = Wp[((size_t)d * KR + rb + k) * O + ocol + o];
    }
    if (tid < 160) eL[tid / 10][tid % 10] = E[(n0 + tid / 10) * 10 + tid % 10];
    __syncthreads();

    const int o2 = tid >> 3;          // 0..31
    const int kv = (tid & 7) * 4;     // 0..28
    for (int ni = 0; ni < 16; ++ni) {
        float ev[10];
        #pragma unroll
        for (int d = 0; d < 10; ++d) ev[d] = eL[ni][d];
        u16 ph[4], pl[4];
        #pragma unroll
        for (int j = 0; j < 4; ++j) {
            float a = 0.f;
            #pragma unroll
            for (int d = 0; d < 10; ++d) a += ev[d] * WpL[d][kv + j][o2];
            u16 hb = f2b(a);
            ph[j] = hb;
            pl[j] = f2b(a - b2f(hb));
        }
        size_t off = ((size_t)(n0 + ni) * O + ocol + o2) * K2 + kc * 32 + kv;
        *(s16x4*)&oh[off] = *(s16x4*)ph;
        *(s16x4*)&ol[off] = *(s16x4*)pl;
    }
}

__global__ __launch_bounds__(256) void k_bias(const float* __restrict__ E, const float* __restrict__ gb0,
                                              const float* __restrict__ ub0, const float* __restrict__ gb1,
                                              const float* __restrict__ ub1, const float* __restrict__ gw0,
                                              const float* __restrict__ uw0,
                                              float* BG0, float* BU0, float* BG1, float* BU1,
                                              float* G0X, float* U0X) {
    __shared__ float e[10];
    int n = blockIdx.x, tid = threadIdx.x;
    if (tid < 10) e[tid] = E[n * 10 + tid];
    __syncthreads();
    if (tid < 128) {
        int o = tid;
        float a0 = 0, a1 = 0, a2 = 0, a3 = 0;
        #pragma unroll
        for (int d = 0; d < 10; ++d) {
            a0 += e[d] * gb0[d * 128 + o];
            a1 += e[d] * gb1[d * 128 + o];
            a2 += e[d] * gw0[((size_t)d * 130 + 0) * 128 + o];
            a3 += e[d] * gw0[((size_t)d * 130 + 65) * 128 + o];
        }
        BG0[n * 128 + o] = a0; BG1[n * 128 + o] = a1;
        G0X[n * 256 + o] = a2; G0X[n * 256 + 128 + o] = a3;
    } else if (tid < 192) {
        int o = tid - 128;
        float a0 = 0, a1 = 0, a2 = 0, a3 = 0;
        #pragma unroll
        for (int d = 0; d < 10; ++d) {
            a0 += e[d] * ub0[d * 64 + o];
            a1 += e[d] * ub1[d * 64 + o];
            a2 += e[d] * uw0[((size_t)d * 130 + 0) * 64 + o];
            a3 += e[d] * uw0[((size_t)d * 130 + 65) * 64 + o];
        }
        BU0[n * 64 + o] = a0; BU1[n * 64 + o] = a1;
        U0X[n * 128 + o] = a2; U0X[n * 128 + 64 + o] = a3;
    }
}

// ---------------- graph GEMM (round-13 prefetch + ROUND-15 epilogue LDS chunk) ----------------
// The beta*B[row] epilogue term needs chunk B[bm..bm+64)[bn..bn+64) — exactly the rows
// loaded during the k0==bm window. Capture those registers to LDS then, instead of
// re-reading 8MB from global in the epilogue. Same bf16 values -> bit-identical output.
__global__ __launch_bounds__(256) void k_gmm(const u16* __restrict__ A, const u16* __restrict__ Bh,
                                             const u16* __restrict__ Bl, const float* __restrict__ dd,
                                             const float* __restrict__ lmax,
                                             u16* __restrict__ Ch, u16* __restrict__ Cl, int N) {
    __shared__ u16 As[64][72];
    __shared__ u16 Bsh[2][64][32];
    __shared__ u16 Bsl[2][64][32];
    __shared__ u16 Ech[2][64][68];    // [plane h/l][row-bm][col-bn] epilogue chunk
    const int tid = threadIdx.x;
    const int w = tid >> 6, l = tid & 63, lr = l & 15, lg = l >> 4;
    const int bm = blockIdx.y * 64, bn = blockIdx.x * 64;
    const int am = tid >> 2, ak = (tid & 3) * 16;
    const int bk = tid >> 3, bn8 = (tid & 7) * 8;
    const int bx = (tid & 7) & 3;
    const int col = ((bk >> 3) ^ bx) * 8 + (bk & 7);
    f32x4 acc[4];
    #pragma unroll
    for (int a = 0; a < 4; ++a) acc[a] = (f32x4){0.f, 0.f, 0.f, 0.f};

    const int nl = w * 16 + lr;
    const int cc = (lg ^ ((nl >> 3) & 3)) * 8;
    const size_t arow = (size_t)(bm + am) * 512;

    s16x8 rA0 = *(const s16x8*)&A[arow + 0 + ak];
    s16x8 rA1 = *(const s16x8*)&A[arow + 0 + ak + 8];
    s16x8 rBh[2], rBl[2];
    #pragma unroll
    for (int hh = 0; hh < 2; ++hh) {
        rBh[hh] = *(const s16x8*)&Bh[(size_t)(0 + hh * 32 + bk) * N + bn + bn8];
        rBl[hh] = *(const s16x8*)&Bl[(size_t)(0 + hh * 32 + bk) * N + bn + bn8];
    }

    for (int k0 = 0; k0 < 512; k0 += 64) {
        *(s16x8*)&As[am][ak]     = rA0;
        *(s16x8*)&As[am][ak + 8] = rA1;
        #pragma unroll
        for (int hh = 0; hh < 2; ++hh) {
            #pragma unroll
            for (int q = 0; q < 8; ++q) {
                Bsh[hh][bn8 + q][col] = ((const u16*)&rBh[hh])[q];
                Bsl[hh][bn8 + q][col] = ((const u16*)&rBl[hh])[q];
            }
        }
        if (k0 == bm) {   // uniform condition: capture epilogue chunk (rows bm..bm+64)
            #pragma unroll
            for (int hh = 0; hh < 2; ++hh) {
                #pragma unroll
                for (int q = 0; q < 8; ++q) {
                    Ech[0][hh * 32 + bk][bn8 + q] = ((const u16*)&rBh[hh])[q];
                    Ech[1][hh * 32 + bk][bn8 + q] = ((const u16*)&rBl[hh])[q];
                }
            }
        }
        __syncthreads();
        if (k0 + 64 < 512) {
            rA0 = *(const s16x8*)&A[arow + k0 + 64 + ak];
            rA1 = *(const s16x8*)&A[arow + k0 + 64 + ak + 8];
            #pragma unroll
            for (int hh = 0; hh < 2; ++hh) {
                rBh[hh] = *(const s16x8*)&Bh[(size_t)(k0 + 64 + hh * 32 + bk) * N + bn + bn8];
                rBl[hh] = *(const s16x8*)&Bl[(size_t)(k0 + 64 + hh * 32 + bk) * N + bn + bn8];
            }
        }
        #pragma unroll
        for (int hh = 0; hh < 2; ++hh) {
            s16x8 bfh = *(const s16x8*)&Bsh[hh][nl][cc];
            s16x8 bfl = *(const s16x8*)&Bsl[hh][nl][cc];
            #pragma unroll
            for (int mf = 0; mf < 4; ++mf) {
                s16x8 afr = *(const s16x8*)&As[mf * 16 + lr][hh * 32 + lg * 8];
                acc[mf] = __builtin_amdgcn_mfma_f32_16x16x32_bf16(afr, bfh, acc[mf], 0, 0, 0);
                acc[mf] = __builtin_amdgcn_mfma_f32_16x16x32_bf16(afr, bfl, acc[mf], 0, 0, 0);
            }
        }
        __syncthreads();
    }
    const float lm = lmax[0], alpha = -2.f / lm;
    const int colg = bn + w * 16 + lr;
    const int ecol = w * 16 + lr;
    #pragma unroll
    for (int mf = 0; mf < 4; ++mf) {
        #pragma unroll
        for (int i = 0; i < 4; ++i) {
            int erow = mf * 16 + lg * 4 + i;
            int rowg = bm + erow;
            size_t off = (size_t)rowg * N + colg;
            float hval = b2f(Ech[0][erow][ecol]) + b2f(Ech[1][erow][ecol]);
            float beta = 2.f * dd[rowg] / lm - 1.f;
            float v = alpha * acc[mf][i] + beta * hval;
            u16 hb = f2b(v);
            Ch[off] = hb;
            Cl[off] = f2b(v - b2f(hb));
        }
    }
}

// ---------------- split-precision MFMA cell (round-9 verified) ----------------
struct CellP {
    const u16 *s0h, *s0l, *s1h, *s1l, *s2h, *s2l, *s3h, *s3l;
    const u16 *Wh, *Wl;
    const float *bias, *wx;
    const u16 *xsh, *xsl, *txh, *txl;
    const u16 *hph, *hpl;
    float* rbuf;
    u16 *oh, *ol;
    int xoff;
};
template <int K2, int O, bool GATE, bool RANK1>
__global__ __launch_bounds__(256) void k_cellp(CellP p) {
    constexpr int NKB = K2 / 32;
    constexpr int MFW = (O == 128) ? 4 : 2;
    const int n = blockIdx.x, tid = threadIdx.x;
    const int w = tid >> 6, l = tid & 63, lr = l & 15, lg = l >> 4;
    const int mbase = (O == 128) ? 0 : ((w >> 1) * 2);
    const int nbase = (O == 128) ? (2 * w) : ((w & 1) * 2);
    f32x4 acc[MFW][2];
    #pragma unroll
    for (int a = 0; a < MFW; ++a)
        #pragma unroll
        for (int c = 0; c < 2; ++c) acc[a][c] = (f32x4){0.f, 0.f, 0.f, 0.f};
    const size_t nb = (size_t)n * 4096;

    #pragma unroll
    for (int kb = 0; kb < NKB; ++kb) {
        const int sg = kb >> 1;
        const u16* sh = sg == 0 ? p.s0h : sg == 1 ? p.s1h : sg == 2 ? p.s2h : p.s3h;
        const u16* sl = sg == 0 ? p.s0l : sg == 1 ? p.s1l : sg == 2 ? p.s2l : p.s3l;
        const int koff = (kb & 1) * 32 + lg * 8;
        s16x8 bfh[2], bfl[2];
        #pragma unroll
        for (int nf = 0; nf < 2; ++nf) {
            int o = (nbase + nf) * 16 + lr;
            size_t wof = ((size_t)n * O + o) * K2 + kb * 32 + lg * 8;
            bfh[nf] = *(const s16x8*)&p.Wh[wof];
            bfl[nf] = *(const s16x8*)&p.Wl[wof];
        }
        #pragma unroll
        for (int mf = 0; mf < MFW; ++mf) {
            int b = (mbase + mf) * 16 + lr;
            s16x8 ah = *(const s16x8*)&sh[nb + b * 64 + koff];
            s16x8 al = *(const s16x8*)&sl[nb + b * 64 + koff];
            #pragma unroll
            for (int nf = 0; nf < 2; ++nf) {
                acc[mf][nf] = __builtin_amdgcn_mfma_f32_16x16x32_bf16(ah, bfh[nf], acc[mf][nf], 0, 0, 0);
                acc[mf][nf] = __builtin_amdgcn_mfma_f32_16x16x32_bf16(ah, bfl[nf], acc[mf][nf], 0, 0, 0);
                acc[mf][nf] = __builtin_amdgcn_mfma_f32_16x16x32_bf16(al, bfh[nf], acc[mf][nf], 0, 0, 0);
            }
        }
    }

    const float* wxn = RANK1 ? (p.wx + (size_t)n * 2 * O) : p.wx;
    #pragma unroll
    for (int mf = 0; mf < MFW; ++mf) {
        #pragma unroll
        for (int i = 0; i < 4; ++i) {
            int b = (mbase + mf) * 16 + lg * 4 + i;
            float xf = 0.f, txf = 0.f;
            if (RANK1) {
                int idx = n * 768 + p.xoff + b;
                xf = b2f(p.xsh[idx]) + b2f(p.xsl[idx]);
                txf = b2f(p.txh[idx]) + b2f(p.txl[idx]);
            }
            #pragma unroll
            for (int nf = 0; nf < 2; ++nf) {
                int o = (nbase + nf) * 16 + lr;
                float s = acc[mf][nf][i] + p.bias[(size_t)n * O + o];
                if (RANK1) s += xf * wxn[o] + txf * wxn[O + o];
                size_t bo = nb + (size_t)b * 64;
                if (GATE) {
                    float v = 1.f / (1.f + expf(-s));
                    if (o < 64) {
                        float hp = b2f(p.hph[bo + o]) + b2f(p.hpl[bo + o]);
                        float zh = v * hp;
                        u16 hb = f2b(zh);
                        p.oh[bo + o] = hb;
                        p.ol[bo + o] = f2b(zh - b2f(hb));
                    } else {
                        p.rbuf[bo + (o - 64)] = v;
                    }
                } else {
                    float hc = tanhf(s);
                    float rv = p.rbuf[bo + o];
                    float hp = b2f(p.oh[bo + o]) + b2f(p.ol[bo + o]);
                    float hn = rv * hp + (1.f - rv) * hc;
                    u16 hb = f2b(hn);
                    p.oh[bo + o] = hb;
                    p.ol[bo + o] = f2b(hn - b2f(hb));
                }
            }
        }
    }
}

// ---------------- end conv ----------------
__global__ __launch_bounds__(256) void k_conv(const u16* __restrict__ hh, const u16* __restrict__ hl,
                                              const float* __restrict__ cw, const float* __restrict__ cb,
                                              float* __restrict__ out) {
    int idx = blockIdx.x * 256 + threadIdx.x;
    int n = idx >> 6, b = idx & 63;
    float hv[64];
    #pragma unroll
    for (int q = 0; q < 8; ++q) {
        s16x8 vh = *(const s16x8*)&hh[(size_t)n * 4096 + b * 64 + q * 8];
        s16x8 vl = *(const s16x8*)&hl[(size_t)n * 4096 + b * 64 + q * 8];
        #pragma unroll
        for (int j = 0; j < 8; ++j) hv[q * 8 + j] = b2f((u16)vh[j]) + b2f((u16)vl[j]);
    }
    #pragma unroll
    for (int t = 0; t < TSEQ; ++t) {
        float s = cb[t];
        #pragma unroll
        for (int j = 0; j < 64; ++j) s += hv[j] * cw[t * 64 + j];
        out[((size_t)b * TSEQ + t) * NN + n] = s;
    }
}

// ---------------- launch ----------------
extern "C" void kernel_launch(void* const* d_in, const int* in_sizes, int n_in,
                              void* d_out, int out_size, void* d_ws, size_t ws_size,
                              hipStream_t stream) {
    const float* gts = (const float*)d_in[0];
    const float* gn  = (const float*)d_in[1];
    const float* E   = (const float*)d_in[2];
    const float* gw0 = (const float*)d_in[3];
    const float* gb0 = (const float*)d_in[4];
    const float* uw0 = (const float*)d_in[5];
    const float* ub0 = (const float*)d_in[6];
    const float* gw1 = (const float*)d_in[7];
    const float* gb1 = (const float*)d_in[8];
    const float* uw1 = (const float*)d_in[9];
    const float* ub1 = (const float*)d_in[10];
    const float* cw  = (const float*)d_in[11];
    const float* cb  = (const float*)d_in[12];
    float* out = (float*)d_out;
    char* ws = (char*)d_ws;

    if (ws_size < WS_BYTES) {
        k_marker<<<1, 64, 0, stream>>>(out, (float)(ws_size >> 20));
        return;
    }

    u16* adjb = (u16*)(ws + B_ADJ);
    float* dd = (float*)(ws + B_DD);
    float* nrm = (float*)(ws + B_NRM);
    float* lmax = (float*)(ws + B_LMAX);
    u16* xsh = (u16*)(ws + B_XSH);
    u16* xsl = (u16*)(ws + B_XSL);
    u16* txh = (u16*)(ws + B_TXH);
    u16* txl = (u16*)(ws + B_TXL);
    u16* h0h  = (u16*)(ws + B_ST + 0 * SZP);
    u16* h0l  = (u16*)(ws + B_ST + 1 * SZP);
    u16* h1h  = (u16*)(ws + B_ST + 2 * SZP);
    u16* h1l  = (u16*)(ws + B_ST + 3 * SZP);
    u16* th0h = (u16*)(ws + B_ST + 4 * SZP);
    u16* th0l = (u16*)(ws + B_ST + 5 * SZP);
    u16* th1h = (u16*)(ws + B_ST + 6 * SZP);
    u16* th1l = (u16*)(ws + B_ST + 7 * SZP);
    u16* zhh  = (u16*)(ws + B_ST + 8 * SZP);
    u16* zhl  = (u16*)(ws + B_ST + 9 * SZP);
    u16* tzh  = (u16*)(ws + B_ST + 10 * SZP);
    u16* tzl  = (u16*)(ws + B_ST + 11 * SZP);
    float* rbuf = (float*)(ws + B_RBUF);
    u16* G0TH = (u16*)(ws + B_G0TH);
    u16* G0TL = (u16*)(ws + B_G0TL);
    u16* U0TH = (u16*)(ws + B_U0TH);
    u16* U0TL = (u16*)(ws + B_U0TL);
    u16* G1TH = (u16*)(ws + B_G1TH);
    u16* G1TL = (u16*)(ws + B_G1TL);
    u16* U1TH = (u16*)(ws + B_U1TH);
    u16* U1TL = (u16*)(ws + B_U1TL);
    float* BG0 = (float*)(ws + B_BG0);
    float* BU0 = (float*)(ws + B_BU0);
    float* BG1 = (float*)(ws + B_BG1);
    float* BU1 = (float*)(ws + B_BU1);
    float* G0X = (float*)(ws + B_G0X);
    float* U0X = (float*)(ws + B_U0X);

    // REPLAY DETERMINISM: zero the ENTIRE used workspace every call (round-8 proven).
    hipMemsetAsync(ws, 0, WS_BYTES, stream);

    k_norm<<<2, 256, 0, stream>>>(E, nrm);
    k_adj<<<NN, 256, 0, stream>>>(E, gn, nrm, adjb, dd);
    k_dmax<<<1, 512, 0, stream>>>(dd, lmax);

    k_xs_bf<<<(NN * TSEQ * BB + 255) / 256, 256, 0, stream>>>(gts, xsh, xsl);
    k_gmm<<<dim3(TSEQ * BB / 64, 8), 256, 0, stream>>>(adjb, xsh, xsl, dd, lmax, txh, txl, TSEQ * BB);

    k_embed2<128, 128, true><<<dim3(32, 4, 4), 256, 0, stream>>>(E, gw0, G0TH, G0TL);
    k_embed2<128, 64, true><<<dim3(32, 4, 2), 256, 0, stream>>>(E, uw0, U0TH, U0TL);
    k_embed2<256, 128, false><<<dim3(32, 8, 4), 256, 0, stream>>>(E, gw1, G1TH, G1TL);
    k_embed2<256, 64, false><<<dim3(32, 8, 2), 256, 0, stream>>>(E, uw1, U1TH, U1TL);
    k_bias<<<512, 256, 0, stream>>>(E, gb0, ub0, gb1, ub1, gw0, uw0,
                                    BG0, BU0, BG1, BU1, G0X, U0X);

    const dim3 gmm_grid(BB * 64 / 64, 8);   // 64x64 tiles -> 512 blocks
    for (int t = 0; t < TSEQ; ++t) {
        int xoff = t * BB;
        CellP g0{h0h, h0l, th0h, th0l, nullptr, nullptr, nullptr, nullptr,
                 G0TH, G0TL, BG0, G0X, xsh, xsl, txh, txl, h0h, h0l, rbuf, zhh, zhl, xoff};
        k_cellp<128, 128, true, true><<<NN, 256, 0, stream>>>(g0);
        k_gmm<<<gmm_grid, 256, 0, stream>>>(adjb, zhh, zhl, dd, lmax, tzh, tzl, 4096);
        CellP u0{zhh, zhl, tzh, tzl, nullptr, nullptr, nullptr, nullptr,
                 U0TH, U0TL, BU0, U0X, xsh, xsl, txh, txl, nullptr, nullptr, rbuf, h0h, h0l, xoff};
        k_cellp<128, 64, false, true><<<NN, 256, 0, stream>>>(u0);
        k_gmm<<<gmm_grid, 256, 0, stream>>>(adjb, h0h, h0l, dd, lmax, th0h, th0l, 4096);
        CellP g1{h0h, h0l, h1h, h1l, th0h, th0l, th1h, th1l,
                 G1TH, G1TL, BG1, nullptr, nullptr, nullptr, nullptr, nullptr, h1h, h1l, rbuf, zhh, zhl, 0};
        k_cellp<256, 128, true, false><<<NN, 256, 0, stream>>>(g1);
        k_gmm<<<gmm_grid, 256, 0, stream>>>(adjb, zhh, zhl, dd, lmax, tzh, tzl, 4096);
        CellP u1{h0h, h0l, zhh, zhl, th0h, th0l, tzh, tzl,
                 U1TH, U1TL, BU1, nullptr, nullptr, nullptr, nullptr, nullptr, nullptr, nullptr, rbuf, h1h, h1l, 0};
        k_cellp<256, 64, false, false><<<NN, 256, 0, stream>>>(u1);
        if (t + 1 < TSEQ)
            k_gmm<<<gmm_grid, 256, 0, stream>>>(adjb, h1h, h1l, dd, lmax, th1h, th1l, 4096);
    }

    k_conv<<<NN * BB / 256, 256, 0, stream>>>(h1h, h1l, cw, cb, out);
}

// Round 16
// 1957.512 us; speedup vs baseline: 1.0522x; 1.0522x over previous
//
#include <hip/hip_runtime.h>
#include <math.h>

#define NN 512
#define TSEQ 12
#define BB 64

typedef unsigned short u16;
typedef short s16x4 __attribute__((ext_vector_type(4)));
typedef short s16x8 __attribute__((ext_vector_type(8)));
typedef float f32x4 __attribute__((ext_vector_type(4)));

__device__ __forceinline__ float b2f(u16 h) { return __uint_as_float(((unsigned)h) << 16); }
__device__ __forceinline__ u16 f2b(float f) {
    unsigned u = __float_as_uint(f);
    return (u16)((u + 0x7FFFu + ((u >> 16) & 1u)) >> 16);
}

// ---------------- workspace layout (bytes) ----------------
constexpr size_t SZP    = (size_t)512 * 4096 * 2;   // one state plane (4 MB)
constexpr size_t B_ADJ  = 0;                        // u16 [512][512] adjacency (0/1, exact bf16)
constexpr size_t B_DD   = B_ADJ + 524288;           // f32 [512] degrees
constexpr size_t B_NRM  = B_DD + 2048;
constexpr size_t B_LMAX = B_NRM + 2048;             // f32 [64]
constexpr size_t B_XSH  = B_LMAX + 256;             // u16 [512][768] x hi
constexpr size_t B_XSL  = B_XSH + 786432;
constexpr size_t B_TXH  = B_XSL + 786432;
constexpr size_t B_TXL  = B_TXH + 786432;
constexpr size_t B_ST   = B_TXL + 786432;           // 12 planes
constexpr size_t B_RBUF = B_ST + 12 * SZP;          // f32 [512][64][64]
constexpr size_t B_G0TH = B_RBUF + 8388608;         // u16 [512][128][128] (fragment-major)
constexpr size_t B_G0TL = B_G0TH + 16777216;
constexpr size_t B_U0TH = B_G0TL + 16777216;        // u16 [512][64][128]
constexpr size_t B_U0TL = B_U0TH + 8388608;
constexpr size_t B_G1TH = B_U0TL + 8388608;         // u16 [512][128][256]
constexpr size_t B_G1TL = B_G1TH + 33554432;
constexpr size_t B_U1TH = B_G1TL + 33554432;        // u16 [512][64][256]
constexpr size_t B_U1TL = B_U1TH + 16777216;
constexpr size_t B_BG0  = B_U1TL + 16777216;        // f32 [512][128]
constexpr size_t B_BU0  = B_BG0 + 262144;           // f32 [512][64]
constexpr size_t B_BG1  = B_BU0 + 131072;
constexpr size_t B_BU1  = B_BG1 + 262144;
constexpr size_t B_G0X  = B_BU1 + 131072;           // f32 [512][2][128]
constexpr size_t B_U0X  = B_G0X + 524288;           // f32 [512][2][64]
constexpr size_t WS_BYTES = B_U0X + 262144;         // ~205 MiB

// ---------------- setup kernels ----------------

__global__ void k_marker(float* out, float v) { out[threadIdx.x] = v; }

__global__ void k_norm(const float* __restrict__ E, float* __restrict__ nrm) {
    int n = blockIdx.x * blockDim.x + threadIdx.x;
    if (n < NN) {
        float s = 0.f;
        #pragma unroll
        for (int q = 0; q < 10; ++q) { float e = E[n * 10 + q]; s += e * e; }
        nrm[n] = sqrtf(s);
    }
}

__global__ __launch_bounds__(256) void k_adj(const float* __restrict__ E, const float* __restrict__ gn,
                                             const float* __restrict__ nrm, u16* __restrict__ adjb,
                                             float* __restrict__ dd) {
    __shared__ float En[10];
    __shared__ float red[256];
    int n = blockIdx.x, tid = threadIdx.x;
    if (tid < 10) En[tid] = E[n * 10 + tid];
    __syncthreads();
    float nn = nrm[n];
    float cnt = 0.f;
    for (int m = tid; m < NN; m += 256) {
        float dot = 0.f;
        #pragma unroll
        for (int q = 0; q < 10; ++q) dot += En[q] * E[m * 10 + q];
        float lg = dot / (nn * nrm[m]);
        lg = (lg + 1.f) * 0.5f;
        float g0 = gn[((size_t)n * NN + m) * 2 + 0];
        float g1 = gn[((size_t)n * NN + m) * 2 + 1];
        bool a = ((lg + g0) >= (1.f - lg + g1) && (m != n));
        adjb[(size_t)n * NN + m] = a ? 0x3F80 : 0;
        cnt += a ? 1.f : 0.f;
    }
    red[tid] = cnt;
    __syncthreads();
    for (int s = 128; s > 0; s >>= 1) { if (tid < s) red[tid] += red[tid + s]; __syncthreads(); }
    if (tid == 0) dd[n] = red[0];
}

__global__ void k_dmax(const float* __restrict__ dd, float* __restrict__ lmax) {
    __shared__ float red[512];
    int t = threadIdx.x;
    red[t] = dd[t];
    __syncthreads();
    for (int s = 256; s > 0; s >>= 1) { if (t < s) red[t] = fmaxf(red[t], red[t + s]); __syncthreads(); }
    if (t == 0) lmax[0] = red[0] + (red[0] > 0.f ? 1.f : 0.f);
}

__global__ __launch_bounds__(256) void k_xs_bf(const float* __restrict__ gts, u16* __restrict__ xh,
                                               u16* __restrict__ xl) {
    int idx = blockIdx.x * 256 + threadIdx.x;
    if (idx >= NN * TSEQ * BB) return;
    int n = idx / (TSEQ * BB);
    int rem = idx - n * (TSEQ * BB);
    int t = rem >> 6, b = rem & 63;
    float v = gts[((size_t)b * NN + n) * TSEQ + t];
    u16 hb = f2b(v);
    xh[idx] = hb;
    xl[idx] = f2b(v - b2f(hb));
}

// ---------------- embed v3: Wp slice in LDS + FRAGMENT-MAJOR weight output ----------------
// ROUND 16: round-15's cell weight loads were 512B-strided per lane (each lane 16B from
// a different cache line -> 1.27 TB/s, the loop's dominant cost). Weights are now stored
// in MFMA B-fragment order: Wfrag[n][o>>4][kb][lane][8], lane = ((k&31)>>3)*16 + (o&15).
// The cell's fragment load becomes one coalesced 1KB wave read. Same values -> bit-identical.
template <int K2, int O, bool SHIFT>
__global__ __launch_bounds__(256) void k_embed2(const float* __restrict__ E, const float* __restrict__ Wp,
                                                u16* __restrict__ oh, u16* __restrict__ ol) {
    constexpr int KR = SHIFT ? 130 : K2;
    constexpr int NKB = K2 / 32;
    __shared__ float WpL[10][32][33];
    __shared__ float eL[16][10];
    const int nc = blockIdx.x, kc = blockIdx.y, oc = blockIdx.z;
    const int tid = threadIdx.x;
    const int rb = kc * 32 + (SHIFT ? (kc >= 2 ? 2 : 1) : 0);
    const int ocol = oc * 32;
    const int n0 = nc * 16;

    for (int el = tid; el < 10 * 32 * 32; el += 256) {
        int d = el >> 10;
        int rem = el & 1023;
        int k = rem >> 5, o = rem & 31;
        WpL[d][k][o] = Wp[((size_t)d * KR + rb + k) * O + ocol + o];
    }
    if (tid < 160) eL[tid / 10][tid % 10] = E[(n0 + tid / 10) * 10 + tid % 10];
    __syncthreads();

    const int o2 = tid >> 3;          // 0..31 (o within 32-col tile)
    const int kv = (tid & 7) * 4;     // 0..28 (k within 32-k block, 4-chunk)
    const int o = ocol + o2;
    const int lane = ((kv >> 3) << 4) + (o & 15);   // kv..kv+3 share one lane 8-run
    const size_t fragbase =
        ((((size_t)0 * (O / 16) + (o >> 4)) * NKB + kc) * 64 + lane) * 8 + (kv & 7);
    const size_t nstride = (size_t)(O / 16) * NKB * 64 * 8;   // = O*K2 per node

    for (int ni = 0; ni < 16; ++ni) {
        float ev[10];
        #pragma unroll
        for (int d = 0; d < 10; ++d) ev[d] = eL[ni][d];
        u16 ph[4], pl[4];
        #pragma unroll
        for (int j = 0; j < 4; ++j) {
            float a = 0.f;
            #pragma unroll
            for (int d = 0; d < 10; ++d) a += ev[d] * WpL[d][kv + j][o2];
            u16 hb = f2b(a);
            ph[j] = hb;
            pl[j] = f2b(a - b2f(hb));
        }
        size_t off = fragbase + (size_t)(n0 + ni) * nstride;
        *(s16x4*)&oh[off] = *(s16x4*)ph;
        *(s16x4*)&ol[off] = *(s16x4*)pl;
    }
}

__global__ __launch_bounds__(256) void k_bias(const float* __restrict__ E, const float* __restrict__ gb0,
                                              const float* __restrict__ ub0, const float* __restrict__ gb1,
                                              const float* __restrict__ ub1, const float* __restrict__ gw0,
                                              const float* __restrict__ uw0,
                                              float* BG0, float* BU0, float* BG1, float* BU1,
                                              float* G0X, float* U0X) {
    __shared__ float e[10];
    int n = blockIdx.x, tid = threadIdx.x;
    if (tid < 10) e[tid] = E[n * 10 + tid];
    __syncthreads();
    if (tid < 128) {
        int o = tid;
        float a0 = 0, a1 = 0, a2 = 0, a3 = 0;
        #pragma unroll
        for (int d = 0; d < 10; ++d) {
            a0 += e[d] * gb0[d * 128 + o];
            a1 += e[d] * gb1[d * 128 + o];
            a2 += e[d] * gw0[((size_t)d * 130 + 0) * 128 + o];
            a3 += e[d] * gw0[((size_t)d * 130 + 65) * 128 + o];
        }
        BG0[n * 128 + o] = a0; BG1[n * 128 + o] = a1;
        G0X[n * 256 + o] = a2; G0X[n * 256 + 128 + o] = a3;
    } else if (tid < 192) {
        int o = tid - 128;
        float a0 = 0, a1 = 0, a2 = 0, a3 = 0;
        #pragma unroll
        for (int d = 0; d < 10; ++d) {
            a0 += e[d] * ub0[d * 64 + o];
            a1 += e[d] * ub1[d * 64 + o];
            a2 += e[d] * uw0[((size_t)d * 130 + 0) * 64 + o];
            a3 += e[d] * uw0[((size_t)d * 130 + 65) * 64 + o];
        }
        BU0[n * 64 + o] = a0; BU1[n * 64 + o] = a1;
        U0X[n * 128 + o] = a2; U0X[n * 128 + 64 + o] = a3;
    }
}

// ---------------- graph GEMM (round-13 prefetch + round-15 epilogue LDS chunk) ----------------
__global__ __launch_bounds__(256) void k_gmm(const u16* __restrict__ A, const u16* __restrict__ Bh,
                                             const u16* __restrict__ Bl, const float* __restrict__ dd,
                                             const float* __restrict__ lmax,
                                             u16* __restrict__ Ch, u16* __restrict__ Cl, int N) {
    __shared__ u16 As[64][72];
    __shared__ u16 Bsh[2][64][32];
    __shared__ u16 Bsl[2][64][32];
    __shared__ u16 Ech[2][64][68];
    const int tid = threadIdx.x;
    const int w = tid >> 6, l = tid & 63, lr = l & 15, lg = l >> 4;
    const int bm = blockIdx.y * 64, bn = blockIdx.x * 64;
    const int am = tid >> 2, ak = (tid & 3) * 16;
    const int bk = tid >> 3, bn8 = (tid & 7) * 8;
    const int bx = (tid & 7) & 3;
    const int col = ((bk >> 3) ^ bx) * 8 + (bk & 7);
    f32x4 acc[4];
    #pragma unroll
    for (int a = 0; a < 4; ++a) acc[a] = (f32x4){0.f, 0.f, 0.f, 0.f};

    const int nl = w * 16 + lr;
    const int cc = (lg ^ ((nl >> 3) & 3)) * 8;
    const size_t arow = (size_t)(bm + am) * 512;

    s16x8 rA0 = *(const s16x8*)&A[arow + 0 + ak];
    s16x8 rA1 = *(const s16x8*)&A[arow + 0 + ak + 8];
    s16x8 rBh[2], rBl[2];
    #pragma unroll
    for (int hh = 0; hh < 2; ++hh) {
        rBh[hh] = *(const s16x8*)&Bh[(size_t)(0 + hh * 32 + bk) * N + bn + bn8];
        rBl[hh] = *(const s16x8*)&Bl[(size_t)(0 + hh * 32 + bk) * N + bn + bn8];
    }

    for (int k0 = 0; k0 < 512; k0 += 64) {
        *(s16x8*)&As[am][ak]     = rA0;
        *(s16x8*)&As[am][ak + 8] = rA1;
        #pragma unroll
        for (int hh = 0; hh < 2; ++hh) {
            #pragma unroll
            for (int q = 0; q < 8; ++q) {
                Bsh[hh][bn8 + q][col] = ((const u16*)&rBh[hh])[q];
                Bsl[hh][bn8 + q][col] = ((const u16*)&rBl[hh])[q];
            }
        }
        if (k0 == bm) {
            #pragma unroll
            for (int hh = 0; hh < 2; ++hh) {
                #pragma unroll
                for (int q = 0; q < 8; ++q) {
                    Ech[0][hh * 32 + bk][bn8 + q] = ((const u16*)&rBh[hh])[q];
                    Ech[1][hh * 32 + bk][bn8 + q] = ((const u16*)&rBl[hh])[q];
                }
            }
        }
        __syncthreads();
        if (k0 + 64 < 512) {
            rA0 = *(const s16x8*)&A[arow + k0 + 64 + ak];
            rA1 = *(const s16x8*)&A[arow + k0 + 64 + ak + 8];
            #pragma unroll
            for (int hh = 0; hh < 2; ++hh) {
                rBh[hh] = *(const s16x8*)&Bh[(size_t)(k0 + 64 + hh * 32 + bk) * N + bn + bn8];
                rBl[hh] = *(const s16x8*)&Bl[(size_t)(k0 + 64 + hh * 32 + bk) * N + bn + bn8];
            }
        }
        #pragma unroll
        for (int hh = 0; hh < 2; ++hh) {
            s16x8 bfh = *(const s16x8*)&Bsh[hh][nl][cc];
            s16x8 bfl = *(const s16x8*)&Bsl[hh][nl][cc];
            #pragma unroll
            for (int mf = 0; mf < 4; ++mf) {
                s16x8 afr = *(const s16x8*)&As[mf * 16 + lr][hh * 32 + lg * 8];
                acc[mf] = __builtin_amdgcn_mfma_f32_16x16x32_bf16(afr, bfh, acc[mf], 0, 0, 0);
                acc[mf] = __builtin_amdgcn_mfma_f32_16x16x32_bf16(afr, bfl, acc[mf], 0, 0, 0);
            }
        }
        __syncthreads();
    }
    const float lm = lmax[0], alpha = -2.f / lm;
    const int colg = bn + w * 16 + lr;
    const int ecol = w * 16 + lr;
    #pragma unroll
    for (int mf = 0; mf < 4; ++mf) {
        #pragma unroll
        for (int i = 0; i < 4; ++i) {
            int erow = mf * 16 + lg * 4 + i;
            int rowg = bm + erow;
            size_t off = (size_t)rowg * N + colg;
            float hval = b2f(Ech[0][erow][ecol]) + b2f(Ech[1][erow][ecol]);
            float beta = 2.f * dd[rowg] / lm - 1.f;
            float v = alpha * acc[mf][i] + beta * hval;
            u16 hb = f2b(v);
            Ch[off] = hb;
            Cl[off] = f2b(v - b2f(hb));
        }
    }
}

// ---------------- split-precision MFMA cell (fragment-major weight loads) ----------------
struct CellP {
    const u16 *s0h, *s0l, *s1h, *s1l, *s2h, *s2l, *s3h, *s3l;
    const u16 *Wh, *Wl;
    const float *bias, *wx;
    const u16 *xsh, *xsl, *txh, *txl;
    const u16 *hph, *hpl;
    float* rbuf;
    u16 *oh, *ol;
    int xoff;
};
template <int K2, int O, bool GATE, bool RANK1>
__global__ __launch_bounds__(256) void k_cellp(CellP p) {
    constexpr int NKB = K2 / 32;
    constexpr int MFW = (O == 128) ? 4 : 2;
    const int n = blockIdx.x, tid = threadIdx.x;
    const int w = tid >> 6, l = tid & 63, lr = l & 15, lg = l >> 4;
    const int mbase = (O == 128) ? 0 : ((w >> 1) * 2);
    const int nbase = (O == 128) ? (2 * w) : ((w & 1) * 2);
    f32x4 acc[MFW][2];
    #pragma unroll
    for (int a = 0; a < MFW; ++a)
        #pragma unroll
        for (int c = 0; c < 2; ++c) acc[a][c] = (f32x4){0.f, 0.f, 0.f, 0.f};
    const size_t nb = (size_t)n * 4096;

    #pragma unroll
    for (int kb = 0; kb < NKB; ++kb) {
        const int sg = kb >> 1;
        const u16* sh = sg == 0 ? p.s0h : sg == 1 ? p.s1h : sg == 2 ? p.s2h : p.s3h;
        const u16* sl = sg == 0 ? p.s0l : sg == 1 ? p.s1l : sg == 2 ? p.s2l : p.s3l;
        const int koff = (kb & 1) * 32 + lg * 8;
        s16x8 bfh[2], bfl[2];
        #pragma unroll
        for (int nf = 0; nf < 2; ++nf) {
            // fragment-major: one coalesced 1KB wave read (lane-indexed)
            size_t wof = ((((size_t)n * (O / 16) + (nbase + nf)) * NKB + kb) * 64 + l) * 8;
            bfh[nf] = *(const s16x8*)&p.Wh[wof];
            bfl[nf] = *(const s16x8*)&p.Wl[wof];
        }
        #pragma unroll
        for (int mf = 0; mf < MFW; ++mf) {
            int b = (mbase + mf) * 16 + lr;
            s16x8 ah = *(const s16x8*)&sh[nb + b * 64 + koff];
            s16x8 al = *(const s16x8*)&sl[nb + b * 64 + koff];
            #pragma unroll
            for (int nf = 0; nf < 2; ++nf) {
                acc[mf][nf] = __builtin_amdgcn_mfma_f32_16x16x32_bf16(ah, bfh[nf], acc[mf][nf], 0, 0, 0);
                acc[mf][nf] = __builtin_amdgcn_mfma_f32_16x16x32_bf16(ah, bfl[nf], acc[mf][nf], 0, 0, 0);
                acc[mf][nf] = __builtin_amdgcn_mfma_f32_16x16x32_bf16(al, bfh[nf], acc[mf][nf], 0, 0, 0);
            }
        }
    }

    const float* wxn = RANK1 ? (p.wx + (size_t)n * 2 * O) : p.wx;
    #pragma unroll
    for (int mf = 0; mf < MFW; ++mf) {
        #pragma unroll
        for (int i = 0; i < 4; ++i) {
            int b = (mbase + mf) * 16 + lg * 4 + i;
            float xf = 0.f, txf = 0.f;
            if (RANK1) {
                int idx = n * 768 + p.xoff + b;
                xf = b2f(p.xsh[idx]) + b2f(p.xsl[idx]);
                txf = b2f(p.txh[idx]) + b2f(p.txl[idx]);
            }
            #pragma unroll
            for (int nf = 0; nf < 2; ++nf) {
                int o = (nbase + nf) * 16 + lr;
                float s = acc[mf][nf][i] + p.bias[(size_t)n * O + o];
                if (RANK1) s += xf * wxn[o] + txf * wxn[O + o];
                size_t bo = nb + (size_t)b * 64;
                if (GATE) {
                    float v = 1.f / (1.f + expf(-s));
                    if (o < 64) {
                        float hp = b2f(p.hph[bo + o]) + b2f(p.hpl[bo + o]);
                        float zh = v * hp;
                        u16 hb = f2b(zh);
                        p.oh[bo + o] = hb;
                        p.ol[bo + o] = f2b(zh - b2f(hb));
                    } else {
                        p.rbuf[bo + (o - 64)] = v;
                    }
                } else {
                    float hc = tanhf(s);
                    float rv = p.rbuf[bo + o];
                    float hp = b2f(p.oh[bo + o]) + b2f(p.ol[bo + o]);
                    float hn = rv * hp + (1.f - rv) * hc;
                    u16 hb = f2b(hn);
                    p.oh[bo + o] = hb;
                    p.ol[bo + o] = f2b(hn - b2f(hb));
                }
            }
        }
    }
}

// ---------------- end conv ----------------
__global__ __launch_bounds__(256) void k_conv(const u16* __restrict__ hh, const u16* __restrict__ hl,
                                              const float* __restrict__ cw, const float* __restrict__ cb,
                                              float* __restrict__ out) {
    int idx = blockIdx.x * 256 + threadIdx.x;
    int n = idx >> 6, b = idx & 63;
    float hv[64];
    #pragma unroll
    for (int q = 0; q < 8; ++q) {
        s16x8 vh = *(const s16x8*)&hh[(size_t)n * 4096 + b * 64 + q * 8];
        s16x8 vl = *(const s16x8*)&hl[(size_t)n * 4096 + b * 64 + q * 8];
        #pragma unroll
        for (int j = 0; j < 8; ++j) hv[q * 8 + j] = b2f((u16)vh[j]) + b2f((u16)vl[j]);
    }
    #pragma unroll
    for (int t = 0; t < TSEQ; ++t) {
        float s = cb[t];
        #pragma unroll
        for (int j = 0; j < 64; ++j) s += hv[j] * cw[t * 64 + j];
        out[((size_t)b * TSEQ + t) * NN + n] = s;
    }
}

// ---------------- launch ----------------
extern "C" void kernel_launch(void* const* d_in, const int* in_sizes, int n_in,
                              void* d_out, int out_size, void* d_ws, size_t ws_size,
                              hipStream_t stream) {
    const float* gts = (const float*)d_in[0];
    const float* gn  = (const float*)d_in[1];
    const float* E   = (const float*)d_in[2];
    const float* gw0 = (const float*)d_in[3];
    const float* gb0 = (const float*)d_in[4];
    const float* uw0 = (const float*)d_in[5];
    const float* ub0 = (const float*)d_in[6];
    const float* gw1 = (const float*)d_in[7];
    const float* gb1 = (const float*)d_in[8];
    const float* uw1 = (const float*)d_in[9];
    const float* ub1 = (const float*)d_in[10];
    const float* cw  = (const float*)d_in[11];
    const float* cb  = (const float*)d_in[12];
    float* out = (float*)d_out;
    char* ws = (char*)d_ws;

    if (ws_size < WS_BYTES) {
        k_marker<<<1, 64, 0, stream>>>(out, (float)(ws_size >> 20));
        return;
    }

    u16* adjb = (u16*)(ws + B_ADJ);
    float* dd = (float*)(ws + B_DD);
    float* nrm = (float*)(ws + B_NRM);
    float* lmax = (float*)(ws + B_LMAX);
    u16* xsh = (u16*)(ws + B_XSH);
    u16* xsl = (u16*)(ws + B_XSL);
    u16* txh = (u16*)(ws + B_TXH);
    u16* txl = (u16*)(ws + B_TXL);
    u16* h0h  = (u16*)(ws + B_ST + 0 * SZP);
    u16* h0l  = (u16*)(ws + B_ST + 1 * SZP);
    u16* h1h  = (u16*)(ws + B_ST + 2 * SZP);
    u16* h1l  = (u16*)(ws + B_ST + 3 * SZP);
    u16* th0h = (u16*)(ws + B_ST + 4 * SZP);
    u16* th0l = (u16*)(ws + B_ST + 5 * SZP);
    u16* th1h = (u16*)(ws + B_ST + 6 * SZP);
    u16* th1l = (u16*)(ws + B_ST + 7 * SZP);
    u16* zhh  = (u16*)(ws + B_ST + 8 * SZP);
    u16* zhl  = (u16*)(ws + B_ST + 9 * SZP);
    u16* tzh  = (u16*)(ws + B_ST + 10 * SZP);
    u16* tzl  = (u16*)(ws + B_ST + 11 * SZP);
    float* rbuf = (float*)(ws + B_RBUF);
    u16* G0TH = (u16*)(ws + B_G0TH);
    u16* G0TL = (u16*)(ws + B_G0TL);
    u16* U0TH = (u16*)(ws + B_U0TH);
    u16* U0TL = (u16*)(ws + B_U0TL);
    u16* G1TH = (u16*)(ws + B_G1TH);
    u16* G1TL = (u16*)(ws + B_G1TL);
    u16* U1TH = (u16*)(ws + B_U1TH);
    u16* U1TL = (u16*)(ws + B_U1TL);
    float* BG0 = (float*)(ws + B_BG0);
    float* BU0 = (float*)(ws + B_BU0);
    float* BG1 = (float*)(ws + B_BG1);
    float* BU1 = (float*)(ws + B_BU1);
    float* G0X = (float*)(ws + B_G0X);
    float* U0X = (float*)(ws + B_U0X);

    // REPLAY DETERMINISM: zero the ENTIRE used workspace every call (round-8 proven).
    hipMemsetAsync(ws, 0, WS_BYTES, stream);

    k_norm<<<2, 256, 0, stream>>>(E, nrm);
    k_adj<<<NN, 256, 0, stream>>>(E, gn, nrm, adjb, dd);
    k_dmax<<<1, 512, 0, stream>>>(dd, lmax);

    k_xs_bf<<<(NN * TSEQ * BB + 255) / 256, 256, 0, stream>>>(gts, xsh, xsl);
    k_gmm<<<dim3(TSEQ * BB / 64, 8), 256, 0, stream>>>(adjb, xsh, xsl, dd, lmax, txh, txl, TSEQ * BB);

    k_embed2<128, 128, true><<<dim3(32, 4, 4), 256, 0, stream>>>(E, gw0, G0TH, G0TL);
    k_embed2<128, 64, true><<<dim3(32, 4, 2), 256, 0, stream>>>(E, uw0, U0TH, U0TL);
    k_embed2<256, 128, false><<<dim3(32, 8, 4), 256, 0, stream>>>(E, gw1, G1TH, G1TL);
    k_embed2<256, 64, false><<<dim3(32, 8, 2), 256, 0, stream>>>(E, uw1, U1TH, U1TL);
    k_bias<<<512, 256, 0, stream>>>(E, gb0, ub0, gb1, ub1, gw0, uw0,
                                    BG0, BU0, BG1, BU1, G0X, U0X);

    const dim3 gmm_grid(BB * 64 / 64, 8);   // 64x64 tiles -> 512 blocks
    for (int t = 0; t < TSEQ; ++t) {
        int xoff = t * BB;
        CellP g0{h0h, h0l, th0h, th0l, nullptr, nullptr, nullptr, nullptr,
                 G0TH, G0TL, BG0, G0X, xsh, xsl, txh, txl, h0h, h0l, rbuf, zhh, zhl, xoff};
        k_cellp<128, 128, true, true><<<NN, 256, 0, stream>>>(g0);
        k_gmm<<<gmm_grid, 256, 0, stream>>>(adjb, zhh, zhl, dd, lmax, tzh, tzl, 4096);
        CellP u0{zhh, zhl, tzh, tzl, nullptr, nullptr, nullptr, nullptr,
                 U0TH, U0TL, BU0, U0X, xsh, xsl, txh, txl, nullptr, nullptr, rbuf, h0h, h0l, xoff};
        k_cellp<128, 64, false, true><<<NN, 256, 0, stream>>>(u0);
        k_gmm<<<gmm_grid, 256, 0, stream>>>(adjb, h0h, h0l, dd, lmax, th0h, th0l, 4096);
        CellP g1{h0h, h0l, h1h, h1l, th0h, th0l, th1h, th1l,
                 G1TH, G1TL, BG1, nullptr, nullptr, nullptr, nullptr, nullptr, h1h, h1l, rbuf, zhh, zhl, 0};
        k_cellp<256, 128, true, false><<<NN, 256, 0, stream>>>(g1);
        k_gmm<<<gmm_grid, 256, 0, stream>>>(adjb, zhh, zhl, dd, lmax, tzh, tzl, 4096);
        CellP u1{h0h, h0l, zhh, zhl, th0h, th0l, tzh, tzl,
                 U1TH, U1TL, BU1, nullptr, nullptr, nullptr, nullptr, nullptr, nullptr, nullptr, rbuf, h1h, h1l, 0};
        k_cellp<256, 64, false, false><<<NN, 256, 0, stream>>>(u1);
        if (t + 1 < TSEQ)
            k_gmm<<<gmm_grid, 256, 0, stream>>>(adjb, h1h, h1l, dd, lmax, th1h, th1l, 4096);
    }

    k_conv<<<NN * BB / 256, 256, 0, stream>>>(h1h, h1l, cw, cb, out);
}

// Round 17
// 1941.893 us; speedup vs baseline: 1.0607x; 1.0080x over previous
//
#include <hip/hip_runtime.h>
#include <math.h>

#define NN 512
#define TSEQ 12
#define BB 64

typedef unsigned short u16;
typedef short s16x4 __attribute__((ext_vector_type(4)));
typedef short s16x8 __attribute__((ext_vector_type(8)));
typedef float f32x4 __attribute__((ext_vector_type(4)));

__device__ __forceinline__ float b2f(u16 h) { return __uint_as_float(((unsigned)h) << 16); }
__device__ __forceinline__ u16 f2b(float f) {
    unsigned u = __float_as_uint(f);
    return (u16)((u + 0x7FFFu + ((u >> 16) & 1u)) >> 16);
}

// ---------------- workspace layout (bytes) ----------------
constexpr size_t SZP    = (size_t)512 * 4096 * 2;   // one state plane (4 MB)
constexpr size_t B_ADJ  = 0;                        // u16 [512][512] adjacency (0/1, exact bf16)
constexpr size_t B_DD   = B_ADJ + 524288;           // f32 [512] degrees
constexpr size_t B_NRM  = B_DD + 2048;
constexpr size_t B_LMAX = B_NRM + 2048;             // f32 [64]
constexpr size_t B_XSH  = B_LMAX + 256;             // u16 [512][768] x hi
constexpr size_t B_XSL  = B_XSH + 786432;
constexpr size_t B_TXH  = B_XSL + 786432;
constexpr size_t B_TXL  = B_TXH + 786432;
constexpr size_t B_ST   = B_TXL + 786432;           // 12 planes
constexpr size_t B_RBUF = B_ST + 12 * SZP;          // f32 [512][64][64]
constexpr size_t B_G0TH = B_RBUF + 8388608;         // u16 (fragment-major weight planes)
constexpr size_t B_G0TL = B_G0TH + 16777216;
constexpr size_t B_U0TH = B_G0TL + 16777216;
constexpr size_t B_U0TL = B_U0TH + 8388608;
constexpr size_t B_G1TH = B_U0TL + 8388608;
constexpr size_t B_G1TL = B_G1TH + 33554432;
constexpr size_t B_U1TH = B_G1TL + 33554432;
constexpr size_t B_U1TL = B_U1TH + 16777216;
constexpr size_t B_BG0  = B_U1TL + 16777216;        // f32 [512][128]
constexpr size_t B_BU0  = B_BG0 + 262144;           // f32 [512][64]
constexpr size_t B_BG1  = B_BU0 + 131072;
constexpr size_t B_BU1  = B_BG1 + 262144;
constexpr size_t B_G0X  = B_BU1 + 131072;           // f32 [512][2][128]
constexpr size_t B_U0X  = B_G0X + 524288;           // f32 [512][2][64]
constexpr size_t WS_BYTES = B_U0X + 262144;         // ~205 MiB

// ---------------- setup kernels ----------------

__global__ void k_marker(float* out, float v) { out[threadIdx.x] = v; }

__global__ void k_norm(const float* __restrict__ E, float* __restrict__ nrm) {
    int n = blockIdx.x * blockDim.x + threadIdx.x;
    if (n < NN) {
        float s = 0.f;
        #pragma unroll
        for (int q = 0; q < 10; ++q) { float e = E[n * 10 + q]; s += e * e; }
        nrm[n] = sqrtf(s);
    }
}

__global__ __launch_bounds__(256) void k_adj(const float* __restrict__ E, const float* __restrict__ gn,
                                             const float* __restrict__ nrm, u16* __restrict__ adjb,
                                             float* __restrict__ dd) {
    __shared__ float En[10];
    __shared__ float red[256];
    int n = blockIdx.x, tid = threadIdx.x;
    if (tid < 10) En[tid] = E[n * 10 + tid];
    __syncthreads();
    float nn = nrm[n];
    float cnt = 0.f;
    for (int m = tid; m < NN; m += 256) {
        float dot = 0.f;
        #pragma unroll
        for (int q = 0; q < 10; ++q) dot += En[q] * E[m * 10 + q];
        float lg = dot / (nn * nrm[m]);
        lg = (lg + 1.f) * 0.5f;
        float g0 = gn[((size_t)n * NN + m) * 2 + 0];
        float g1 = gn[((size_t)n * NN + m) * 2 + 1];
        bool a = ((lg + g0) >= (1.f - lg + g1) && (m != n));
        adjb[(size_t)n * NN + m] = a ? 0x3F80 : 0;
        cnt += a ? 1.f : 0.f;
    }
    red[tid] = cnt;
    __syncthreads();
    for (int s = 128; s > 0; s >>= 1) { if (tid < s) red[tid] += red[tid + s]; __syncthreads(); }
    if (tid == 0) dd[n] = red[0];
}

__global__ void k_dmax(const float* __restrict__ dd, float* __restrict__ lmax) {
    __shared__ float red[512];
    int t = threadIdx.x;
    red[t] = dd[t];
    __syncthreads();
    for (int s = 256; s > 0; s >>= 1) { if (t < s) red[t] = fmaxf(red[t], red[t + s]); __syncthreads(); }
    if (t == 0) lmax[0] = red[0] + (red[0] > 0.f ? 1.f : 0.f);
}

__global__ __launch_bounds__(256) void k_xs_bf(const float* __restrict__ gts, u16* __restrict__ xh,
                                               u16* __restrict__ xl) {
    int idx = blockIdx.x * 256 + threadIdx.x;
    if (idx >= NN * TSEQ * BB) return;
    int n = idx / (TSEQ * BB);
    int rem = idx - n * (TSEQ * BB);
    int t = rem >> 6, b = rem & 63;
    float v = gts[((size_t)b * NN + n) * TSEQ + t];
    u16 hb = f2b(v);
    xh[idx] = hb;
    xl[idx] = f2b(v - b2f(hb));
}

// ---------------- embed v3 (round-16): Wp in LDS + fragment-major output ----------------
template <int K2, int O, bool SHIFT>
__global__ __launch_bounds__(256) void k_embed2(const float* __restrict__ E, const float* __restrict__ Wp,
                                                u16* __restrict__ oh, u16* __restrict__ ol) {
    constexpr int KR = SHIFT ? 130 : K2;
    constexpr int NKB = K2 / 32;
    __shared__ float WpL[10][32][33];
    __shared__ float eL[16][10];
    const int nc = blockIdx.x, kc = blockIdx.y, oc = blockIdx.z;
    const int tid = threadIdx.x;
    const int rb = kc * 32 + (SHIFT ? (kc >= 2 ? 2 : 1) : 0);
    const int ocol = oc * 32;
    const int n0 = nc * 16;

    for (int el = tid; el < 10 * 32 * 32; el += 256) {
        int d = el >> 10;
        int rem = el & 1023;
        int k = rem >> 5, o = rem & 31;
        WpL[d][k][o] = Wp[((size_t)d * KR + rb + k) * O + ocol + o];
    }
    if (tid < 160) eL[tid / 10][tid % 10] = E[(n0 + tid / 10) * 10 + tid % 10];
    __syncthreads();

    const int o2 = tid >> 3;
    const int kv = (tid & 7) * 4;
    const int o = ocol + o2;
    const int lane = ((kv >> 3) << 4) + (o & 15);
    const size_t fragbase =
        ((((size_t)0 * (O / 16) + (o >> 4)) * NKB + kc) * 64 + lane) * 8 + (kv & 7);
    const size_t nstride = (size_t)(O / 16) * NKB * 64 * 8;

    for (int ni = 0; ni < 16; ++ni) {
        float ev[10];
        #pragma unroll
        for (int d = 0; d < 10; ++d) ev[d] = eL[ni][d];
        u16 ph[4], pl[4];
        #pragma unroll
        for (int j = 0; j < 4; ++j) {
            float a = 0.f;
            #pragma unroll
            for (int d = 0; d < 10; ++d) a += ev[d] * WpL[d][kv + j][o2];
            u16 hb = f2b(a);
            ph[j] = hb;
            pl[j] = f2b(a - b2f(hb));
        }
        size_t off = fragbase + (size_t)(n0 + ni) * nstride;
        *(s16x4*)&oh[off] = *(s16x4*)ph;
        *(s16x4*)&ol[off] = *(s16x4*)pl;
    }
}

__global__ __launch_bounds__(256) void k_bias(const float* __restrict__ E, const float* __restrict__ gb0,
                                              const float* __restrict__ ub0, const float* __restrict__ gb1,
                                              const float* __restrict__ ub1, const float* __restrict__ gw0,
                                              const float* __restrict__ uw0,
                                              float* BG0, float* BU0, float* BG1, float* BU1,
                                              float* G0X, float* U0X) {
    __shared__ float e[10];
    int n = blockIdx.x, tid = threadIdx.x;
    if (tid < 10) e[tid] = E[n * 10 + tid];
    __syncthreads();
    if (tid < 128) {
        int o = tid;
        float a0 = 0, a1 = 0, a2 = 0, a3 = 0;
        #pragma unroll
        for (int d = 0; d < 10; ++d) {
            a0 += e[d] * gb0[d * 128 + o];
            a1 += e[d] * gb1[d * 128 + o];
            a2 += e[d] * gw0[((size_t)d * 130 + 0) * 128 + o];
            a3 += e[d] * gw0[((size_t)d * 130 + 65) * 128 + o];
        }
        BG0[n * 128 + o] = a0; BG1[n * 128 + o] = a1;
        G0X[n * 256 + o] = a2; G0X[n * 256 + 128 + o] = a3;
    } else if (tid < 192) {
        int o = tid - 128;
        float a0 = 0, a1 = 0, a2 = 0, a3 = 0;
        #pragma unroll
        for (int d = 0; d < 10; ++d) {
            a0 += e[d] * ub0[d * 64 + o];
            a1 += e[d] * ub1[d * 64 + o];
            a2 += e[d] * uw0[((size_t)d * 130 + 0) * 64 + o];
            a3 += e[d] * uw0[((size_t)d * 130 + 65) * 64 + o];
        }
        BU0[n * 64 + o] = a0; BU1[n * 64 + o] = a1;
        U0X[n * 128 + o] = a2; U0X[n * 128 + 64 + o] = a3;
    }
}

// ---------------- graph GEMM: ROUND 17 single-barrier double-buffered LDS ----------------
// Stages alternate between LDS buffer 0/1; each k-iteration issues next loads, runs MFMAs
// from buf[cur] (hiding load latency), stages buf[cur^1], then ONE barrier (was 2).
// WAR hazard on buf[cur^1] is fenced by the PREVIOUS iteration's barrier. Per-window
// accumulation order unchanged -> bit-identical output. Epilogue reads B from global
// (round-15 LDS chunk reverted: measured neutral; frees LDS for 3 blocks/CU).
__global__ __launch_bounds__(256) void k_gmm(const u16* __restrict__ A, const u16* __restrict__ Bh,
                                             const u16* __restrict__ Bl, const float* __restrict__ dd,
                                             const float* __restrict__ lmax,
                                             u16* __restrict__ Ch, u16* __restrict__ Cl, int N) {
    __shared__ u16 As[2][64][72];
    __shared__ u16 Bsh[2][2][64][32];
    __shared__ u16 Bsl[2][2][64][32];
    const int tid = threadIdx.x;
    const int w = tid >> 6, l = tid & 63, lr = l & 15, lg = l >> 4;
    const int bm = blockIdx.y * 64, bn = blockIdx.x * 64;
    const int am = tid >> 2, ak = (tid & 3) * 16;
    const int bk = tid >> 3, bn8 = (tid & 7) * 8;
    const int bx = (tid & 7) & 3;
    const int col = ((bk >> 3) ^ bx) * 8 + (bk & 7);
    f32x4 acc[4];
    #pragma unroll
    for (int a = 0; a < 4; ++a) acc[a] = (f32x4){0.f, 0.f, 0.f, 0.f};

    const int nl = w * 16 + lr;
    const int cc = (lg ^ ((nl >> 3) & 3)) * 8;
    const size_t arow = (size_t)(bm + am) * 512;

    s16x8 rA0, rA1, rBh[2], rBl[2];
    // prologue: load + stage k0=0 into buffer 0
    rA0 = *(const s16x8*)&A[arow + 0 + ak];
    rA1 = *(const s16x8*)&A[arow + 0 + ak + 8];
    #pragma unroll
    for (int hh = 0; hh < 2; ++hh) {
        rBh[hh] = *(const s16x8*)&Bh[(size_t)(0 + hh * 32 + bk) * N + bn + bn8];
        rBl[hh] = *(const s16x8*)&Bl[(size_t)(0 + hh * 32 + bk) * N + bn + bn8];
    }
    *(s16x8*)&As[0][am][ak]     = rA0;
    *(s16x8*)&As[0][am][ak + 8] = rA1;
    #pragma unroll
    for (int hh = 0; hh < 2; ++hh) {
        #pragma unroll
        for (int q = 0; q < 8; ++q) {
            Bsh[0][hh][bn8 + q][col] = ((const u16*)&rBh[hh])[q];
            Bsl[0][hh][bn8 + q][col] = ((const u16*)&rBl[hh])[q];
        }
    }
    __syncthreads();

    for (int k0 = 0; k0 < 512; k0 += 64) {
        const int cur = (k0 >> 6) & 1;
        const bool more = (k0 + 64 < 512);
        if (more) {
            rA0 = *(const s16x8*)&A[arow + k0 + 64 + ak];
            rA1 = *(const s16x8*)&A[arow + k0 + 64 + ak + 8];
            #pragma unroll
            for (int hh = 0; hh < 2; ++hh) {
                rBh[hh] = *(const s16x8*)&Bh[(size_t)(k0 + 64 + hh * 32 + bk) * N + bn + bn8];
                rBl[hh] = *(const s16x8*)&Bl[(size_t)(k0 + 64 + hh * 32 + bk) * N + bn + bn8];
            }
        }
        #pragma unroll
        for (int hh = 0; hh < 2; ++hh) {
            s16x8 bfh = *(const s16x8*)&Bsh[cur][hh][nl][cc];
            s16x8 bfl = *(const s16x8*)&Bsl[cur][hh][nl][cc];
            #pragma unroll
            for (int mf = 0; mf < 4; ++mf) {
                s16x8 afr = *(const s16x8*)&As[cur][mf * 16 + lr][hh * 32 + lg * 8];
                acc[mf] = __builtin_amdgcn_mfma_f32_16x16x32_bf16(afr, bfh, acc[mf], 0, 0, 0);
                acc[mf] = __builtin_amdgcn_mfma_f32_16x16x32_bf16(afr, bfl, acc[mf], 0, 0, 0);
            }
        }
        if (more) {
            const int nxt = cur ^ 1;
            *(s16x8*)&As[nxt][am][ak]     = rA0;
            *(s16x8*)&As[nxt][am][ak + 8] = rA1;
            #pragma unroll
            for (int hh = 0; hh < 2; ++hh) {
                #pragma unroll
                for (int q = 0; q < 8; ++q) {
                    Bsh[nxt][hh][bn8 + q][col] = ((const u16*)&rBh[hh])[q];
                    Bsl[nxt][hh][bn8 + q][col] = ((const u16*)&rBl[hh])[q];
                }
            }
        }
        __syncthreads();
    }
    const float lm = lmax[0], alpha = -2.f / lm;
    const int colg = bn + w * 16 + lr;
    #pragma unroll
    for (int mf = 0; mf < 4; ++mf) {
        #pragma unroll
        for (int i = 0; i < 4; ++i) {
            int rowg = bm + mf * 16 + lg * 4 + i;
            size_t off = (size_t)rowg * N + colg;
            float hval = b2f(Bh[off]) + b2f(Bl[off]);
            float beta = 2.f * dd[rowg] / lm - 1.f;
            float v = alpha * acc[mf][i] + beta * hval;
            u16 hb = f2b(v);
            Ch[off] = hb;
            Cl[off] = f2b(v - b2f(hb));
        }
    }
}

// ---------------- split-precision MFMA cell (round-16 fragment-major) ----------------
struct CellP {
    const u16 *s0h, *s0l, *s1h, *s1l, *s2h, *s2l, *s3h, *s3l;
    const u16 *Wh, *Wl;
    const float *bias, *wx;
    const u16 *xsh, *xsl, *txh, *txl;
    const u16 *hph, *hpl;
    float* rbuf;
    u16 *oh, *ol;
    int xoff;
};
template <int K2, int O, bool GATE, bool RANK1>
__global__ __launch_bounds__(256) void k_cellp(CellP p) {
    constexpr int NKB = K2 / 32;
    constexpr int MFW = (O == 128) ? 4 : 2;
    const int n = blockIdx.x, tid = threadIdx.x;
    const int w = tid >> 6, l = tid & 63, lr = l & 15, lg = l >> 4;
    const int mbase = (O == 128) ? 0 : ((w >> 1) * 2);
    const int nbase = (O == 128) ? (2 * w) : ((w & 1) * 2);
    f32x4 acc[MFW][2];
    #pragma unroll
    for (int a = 0; a < MFW; ++a)
        #pragma unroll
        for (int c = 0; c < 2; ++c) acc[a][c] = (f32x4){0.f, 0.f, 0.f, 0.f};
    const size_t nb = (size_t)n * 4096;

    #pragma unroll
    for (int kb = 0; kb < NKB; ++kb) {
        const int sg = kb >> 1;
        const u16* sh = sg == 0 ? p.s0h : sg == 1 ? p.s1h : sg == 2 ? p.s2h : p.s3h;
        const u16* sl = sg == 0 ? p.s0l : sg == 1 ? p.s1l : sg == 2 ? p.s2l : p.s3l;
        const int koff = (kb & 1) * 32 + lg * 8;
        s16x8 bfh[2], bfl[2];
        #pragma unroll
        for (int nf = 0; nf < 2; ++nf) {
            size_t wof = ((((size_t)n * (O / 16) + (nbase + nf)) * NKB + kb) * 64 + l) * 8;
            bfh[nf] = *(const s16x8*)&p.Wh[wof];
            bfl[nf] = *(const s16x8*)&p.Wl[wof];
        }
        #pragma unroll
        for (int mf = 0; mf < MFW; ++mf) {
            int b = (mbase + mf) * 16 + lr;
            s16x8 ah = *(const s16x8*)&sh[nb + b * 64 + koff];
            s16x8 al = *(const s16x8*)&sl[nb + b * 64 + koff];
            #pragma unroll
            for (int nf = 0; nf < 2; ++nf) {
                acc[mf][nf] = __builtin_amdgcn_mfma_f32_16x16x32_bf16(ah, bfh[nf], acc[mf][nf], 0, 0, 0);
                acc[mf][nf] = __builtin_amdgcn_mfma_f32_16x16x32_bf16(ah, bfl[nf], acc[mf][nf], 0, 0, 0);
                acc[mf][nf] = __builtin_amdgcn_mfma_f32_16x16x32_bf16(al, bfh[nf], acc[mf][nf], 0, 0, 0);
            }
        }
    }

    const float* wxn = RANK1 ? (p.wx + (size_t)n * 2 * O) : p.wx;
    #pragma unroll
    for (int mf = 0; mf < MFW; ++mf) {
        #pragma unroll
        for (int i = 0; i < 4; ++i) {
            int b = (mbase + mf) * 16 + lg * 4 + i;
            float xf = 0.f, txf = 0.f;
            if (RANK1) {
                int idx = n * 768 + p.xoff + b;
                xf = b2f(p.xsh[idx]) + b2f(p.xsl[idx]);
                txf = b2f(p.txh[idx]) + b2f(p.txl[idx]);
            }
            #pragma unroll
            for (int nf = 0; nf < 2; ++nf) {
                int o = (nbase + nf) * 16 + lr;
                float s = acc[mf][nf][i] + p.bias[(size_t)n * O + o];
                if (RANK1) s += xf * wxn[o] + txf * wxn[O + o];
                size_t bo = nb + (size_t)b * 64;
                if (GATE) {
                    float v = 1.f / (1.f + expf(-s));
                    if (o < 64) {
                        float hp = b2f(p.hph[bo + o]) + b2f(p.hpl[bo + o]);
                        float zh = v * hp;
                        u16 hb = f2b(zh);
                        p.oh[bo + o] = hb;
                        p.ol[bo + o] = f2b(zh - b2f(hb));
                    } else {
                        p.rbuf[bo + (o - 64)] = v;
                    }
                } else {
                    float hc = tanhf(s);
                    float rv = p.rbuf[bo + o];
                    float hp = b2f(p.oh[bo + o]) + b2f(p.ol[bo + o]);
                    float hn = rv * hp + (1.f - rv) * hc;
                    u16 hb = f2b(hn);
                    p.oh[bo + o] = hb;
                    p.ol[bo + o] = f2b(hn - b2f(hb));
                }
            }
        }
    }
}

// ---------------- end conv ----------------
__global__ __launch_bounds__(256) void k_conv(const u16* __restrict__ hh, const u16* __restrict__ hl,
                                              const float* __restrict__ cw, const float* __restrict__ cb,
                                              float* __restrict__ out) {
    int idx = blockIdx.x * 256 + threadIdx.x;
    int n = idx >> 6, b = idx & 63;
    float hv[64];
    #pragma unroll
    for (int q = 0; q < 8; ++q) {
        s16x8 vh = *(const s16x8*)&hh[(size_t)n * 4096 + b * 64 + q * 8];
        s16x8 vl = *(const s16x8*)&hl[(size_t)n * 4096 + b * 64 + q * 8];
        #pragma unroll
        for (int j = 0; j < 8; ++j) hv[q * 8 + j] = b2f((u16)vh[j]) + b2f((u16)vl[j]);
    }
    #pragma unroll
    for (int t = 0; t < TSEQ; ++t) {
        float s = cb[t];
        #pragma unroll
        for (int j = 0; j < 64; ++j) s += hv[j] * cw[t * 64 + j];
        out[((size_t)b * TSEQ + t) * NN + n] = s;
    }
}

// ---------------- launch ----------------
extern "C" void kernel_launch(void* const* d_in, const int* in_sizes, int n_in,
                              void* d_out, int out_size, void* d_ws, size_t ws_size,
                              hipStream_t stream) {
    const float* gts = (const float*)d_in[0];
    const float* gn  = (const float*)d_in[1];
    const float* E   = (const float*)d_in[2];
    const float* gw0 = (const float*)d_in[3];
    const float* gb0 = (const float*)d_in[4];
    const float* uw0 = (const float*)d_in[5];
    const float* ub0 = (const float*)d_in[6];
    const float* gw1 = (const float*)d_in[7];
    const float* gb1 = (const float*)d_in[8];
    const float* uw1 = (const float*)d_in[9];
    const float* ub1 = (const float*)d_in[10];
    const float* cw  = (const float*)d_in[11];
    const float* cb  = (const float*)d_in[12];
    float* out = (float*)d_out;
    char* ws = (char*)d_ws;

    if (ws_size < WS_BYTES) {
        k_marker<<<1, 64, 0, stream>>>(out, (float)(ws_size >> 20));
        return;
    }

    u16* adjb = (u16*)(ws + B_ADJ);
    float* dd = (float*)(ws + B_DD);
    float* nrm = (float*)(ws + B_NRM);
    float* lmax = (float*)(ws + B_LMAX);
    u16* xsh = (u16*)(ws + B_XSH);
    u16* xsl = (u16*)(ws + B_XSL);
    u16* txh = (u16*)(ws + B_TXH);
    u16* txl = (u16*)(ws + B_TXL);
    u16* h0h  = (u16*)(ws + B_ST + 0 * SZP);
    u16* h0l  = (u16*)(ws + B_ST + 1 * SZP);
    u16* h1h  = (u16*)(ws + B_ST + 2 * SZP);
    u16* h1l  = (u16*)(ws + B_ST + 3 * SZP);
    u16* th0h = (u16*)(ws + B_ST + 4 * SZP);
    u16* th0l = (u16*)(ws + B_ST + 5 * SZP);
    u16* th1h = (u16*)(ws + B_ST + 6 * SZP);
    u16* th1l = (u16*)(ws + B_ST + 7 * SZP);
    u16* zhh  = (u16*)(ws + B_ST + 8 * SZP);
    u16* zhl  = (u16*)(ws + B_ST + 9 * SZP);
    u16* tzh  = (u16*)(ws + B_ST + 10 * SZP);
    u16* tzl  = (u16*)(ws + B_ST + 11 * SZP);
    float* rbuf = (float*)(ws + B_RBUF);
    u16* G0TH = (u16*)(ws + B_G0TH);
    u16* G0TL = (u16*)(ws + B_G0TL);
    u16* U0TH = (u16*)(ws + B_U0TH);
    u16* U0TL = (u16*)(ws + B_U0TL);
    u16* G1TH = (u16*)(ws + B_G1TH);
    u16* G1TL = (u16*)(ws + B_G1TL);
    u16* U1TH = (u16*)(ws + B_U1TH);
    u16* U1TL = (u16*)(ws + B_U1TL);
    float* BG0 = (float*)(ws + B_BG0);
    float* BU0 = (float*)(ws + B_BU0);
    float* BG1 = (float*)(ws + B_BG1);
    float* BU1 = (float*)(ws + B_BU1);
    float* G0X = (float*)(ws + B_G0X);
    float* U0X = (float*)(ws + B_U0X);

    // REPLAY DETERMINISM: zero the ENTIRE used workspace every call (round-8 proven).
    hipMemsetAsync(ws, 0, WS_BYTES, stream);

    k_norm<<<2, 256, 0, stream>>>(E, nrm);
    k_adj<<<NN, 256, 0, stream>>>(E, gn, nrm, adjb, dd);
    k_dmax<<<1, 512, 0, stream>>>(dd, lmax);

    k_xs_bf<<<(NN * TSEQ * BB + 255) / 256, 256, 0, stream>>>(gts, xsh, xsl);
    k_gmm<<<dim3(TSEQ * BB / 64, 8), 256, 0, stream>>>(adjb, xsh, xsl, dd, lmax, txh, txl, TSEQ * BB);

    k_embed2<128, 128, true><<<dim3(32, 4, 4), 256, 0, stream>>>(E, gw0, G0TH, G0TL);
    k_embed2<128, 64, true><<<dim3(32, 4, 2), 256, 0, stream>>>(E, uw0, U0TH, U0TL);
    k_embed2<256, 128, false><<<dim3(32, 8, 4), 256, 0, stream>>>(E, gw1, G1TH, G1TL);
    k_embed2<256, 64, false><<<dim3(32, 8, 2), 256, 0, stream>>>(E, uw1, U1TH, U1TL);
    k_bias<<<512, 256, 0, stream>>>(E, gb0, ub0, gb1, ub1, gw0, uw0,
                                    BG0, BU0, BG1, BU1, G0X, U0X);

    const dim3 gmm_grid(BB * 64 / 64, 8);   // 64x64 tiles -> 512 blocks
    for (int t = 0; t < TSEQ; ++t) {
        int xoff = t * BB;
        CellP g0{h0h, h0l, th0h, th0l, nullptr, nullptr, nullptr, nullptr,
                 G0TH, G0TL, BG0, G0X, xsh, xsl, txh, txl, h0h, h0l, rbuf, zhh, zhl, xoff};
        k_cellp<128, 128, true, true><<<NN, 256, 0, stream>>>(g0);
        k_gmm<<<gmm_grid, 256, 0, stream>>>(adjb, zhh, zhl, dd, lmax, tzh, tzl, 4096);
        CellP u0{zhh, zhl, tzh, tzl, nullptr, nullptr, nullptr, nullptr,
                 U0TH, U0TL, BU0, U0X, xsh, xsl, txh, txl, nullptr, nullptr, rbuf, h0h, h0l, xoff};
        k_cellp<128, 64, false, true><<<NN, 256, 0, stream>>>(u0);
        k_gmm<<<gmm_grid, 256, 0, stream>>>(adjb, h0h, h0l, dd, lmax, th0h, th0l, 4096);
        CellP g1{h0h, h0l, h1h, h1l, th0h, th0l, th1h, th1l,
                 G1TH, G1TL, BG1, nullptr, nullptr, nullptr, nullptr, nullptr, h1h, h1l, rbuf, zhh, zhl, 0};
        k_cellp<256, 128, true, false><<<NN, 256, 0, stream>>>(g1);
        k_gmm<<<gmm_grid, 256, 0, stream>>>(adjb, zhh, zhl, dd, lmax, tzh, tzl, 4096);
        CellP u1{h0h, h0l, zhh, zhl, th0h, th0l, tzh, tzl,
                 U1TH, U1TL, BU1, nullptr, nullptr, nullptr, nullptr, nullptr, nullptr, nullptr, rbuf, h1h, h1l, 0};
        k_cellp<256, 64, false, false><<<NN, 256, 0, stream>>>(u1);
        if (t + 1 < TSEQ)
            k_gmm<<<gmm_grid, 256, 0, stream>>>(adjb, h1h, h1l, dd, lmax, th1h, th1l, 4096);
    }

    k_conv<<<NN * BB / 256, 256, 0, stream>>>(h1h, h1l, cw, cb, out);
}

// Round 18
// 1864.382 us; speedup vs baseline: 1.1047x; 1.0416x over previous
//
#include <hip/hip_runtime.h>
#include <math.h>

#define NN 512
#define TSEQ 12
#define BB 64

typedef unsigned short u16;
typedef short s16x4 __attribute__((ext_vector_type(4)));
typedef short s16x8 __attribute__((ext_vector_type(8)));
typedef float f32x4 __attribute__((ext_vector_type(4)));

__device__ __forceinline__ float b2f(u16 h) { return __uint_as_float(((unsigned)h) << 16); }
__device__ __forceinline__ u16 f2b(float f) {
    unsigned u = __float_as_uint(f);
    return (u16)((u + 0x7FFFu + ((u >> 16) & 1u)) >> 16);
}

// ---------------- workspace layout (bytes) ----------------
constexpr size_t SZP    = (size_t)512 * 4096 * 2;   // one state plane (4 MB)
constexpr size_t B_ADJ  = 0;
constexpr size_t B_DD   = B_ADJ + 524288;
constexpr size_t B_NRM  = B_DD + 2048;
constexpr size_t B_LMAX = B_NRM + 2048;
constexpr size_t B_XSH  = B_LMAX + 256;
constexpr size_t B_XSL  = B_XSH + 786432;
constexpr size_t B_TXH  = B_XSL + 786432;
constexpr size_t B_TXL  = B_TXH + 786432;
constexpr size_t B_ST   = B_TXL + 786432;           // 12 planes
constexpr size_t B_RBUF = B_ST + 12 * SZP;
constexpr size_t B_G0TH = B_RBUF + 8388608;
constexpr size_t B_G0TL = B_G0TH + 16777216;
constexpr size_t B_U0TH = B_G0TL + 16777216;
constexpr size_t B_U0TL = B_U0TH + 8388608;
constexpr size_t B_G1TH = B_U0TL + 8388608;
constexpr size_t B_G1TL = B_G1TH + 33554432;
constexpr size_t B_U1TH = B_G1TL + 33554432;
constexpr size_t B_U1TL = B_U1TH + 16777216;
constexpr size_t B_BG0  = B_U1TL + 16777216;
constexpr size_t B_BU0  = B_BG0 + 262144;
constexpr size_t B_BG1  = B_BU0 + 131072;
constexpr size_t B_BU1  = B_BG1 + 262144;
constexpr size_t B_G0X  = B_BU1 + 131072;
constexpr size_t B_U0X  = B_G0X + 524288;
constexpr size_t WS_BYTES = B_U0X + 262144;         // ~205 MiB

// ---------------- setup kernels ----------------

__global__ void k_marker(float* out, float v) { out[threadIdx.x] = v; }

__global__ void k_norm(const float* __restrict__ E, float* __restrict__ nrm) {
    int n = blockIdx.x * blockDim.x + threadIdx.x;
    if (n < NN) {
        float s = 0.f;
        #pragma unroll
        for (int q = 0; q < 10; ++q) { float e = E[n * 10 + q]; s += e * e; }
        nrm[n] = sqrtf(s);
    }
}

__global__ __launch_bounds__(256) void k_adj(const float* __restrict__ E, const float* __restrict__ gn,
                                             const float* __restrict__ nrm, u16* __restrict__ adjb,
                                             float* __restrict__ dd) {
    __shared__ float En[10];
    __shared__ float red[256];
    int n = blockIdx.x, tid = threadIdx.x;
    if (tid < 10) En[tid] = E[n * 10 + tid];
    __syncthreads();
    float nn = nrm[n];
    float cnt = 0.f;
    for (int m = tid; m < NN; m += 256) {
        float dot = 0.f;
        #pragma unroll
        for (int q = 0; q < 10; ++q) dot += En[q] * E[m * 10 + q];
        float lg = dot / (nn * nrm[m]);
        lg = (lg + 1.f) * 0.5f;
        float g0 = gn[((size_t)n * NN + m) * 2 + 0];
        float g1 = gn[((size_t)n * NN + m) * 2 + 1];
        bool a = ((lg + g0) >= (1.f - lg + g1) && (m != n));
        adjb[(size_t)n * NN + m] = a ? 0x3F80 : 0;
        cnt += a ? 1.f : 0.f;
    }
    red[tid] = cnt;
    __syncthreads();
    for (int s = 128; s > 0; s >>= 1) { if (tid < s) red[tid] += red[tid + s]; __syncthreads(); }
    if (tid == 0) dd[n] = red[0];
}

__global__ void k_dmax(const float* __restrict__ dd, float* __restrict__ lmax) {
    __shared__ float red[512];
    int t = threadIdx.x;
    red[t] = dd[t];
    __syncthreads();
    for (int s = 256; s > 0; s >>= 1) { if (t < s) red[t] = fmaxf(red[t], red[t + s]); __syncthreads(); }
    if (t == 0) lmax[0] = red[0] + (red[0] > 0.f ? 1.f : 0.f);
}

__global__ __launch_bounds__(256) void k_xs_bf(const float* __restrict__ gts, u16* __restrict__ xh,
                                               u16* __restrict__ xl) {
    int idx = blockIdx.x * 256 + threadIdx.x;
    if (idx >= NN * TSEQ * BB) return;
    int n = idx / (TSEQ * BB);
    int rem = idx - n * (TSEQ * BB);
    int t = rem >> 6, b = rem & 63;
    float v = gts[((size_t)b * NN + n) * TSEQ + t];
    u16 hb = f2b(v);
    xh[idx] = hb;
    xl[idx] = f2b(v - b2f(hb));
}

// ---------------- embed v3 (round-16): Wp in LDS + fragment-major output ----------------
template <int K2, int O, bool SHIFT>
__global__ __launch_bounds__(256) void k_embed2(const float* __restrict__ E, const float* __restrict__ Wp,
                                                u16* __restrict__ oh, u16* __restrict__ ol) {
    constexpr int KR = SHIFT ? 130 : K2;
    constexpr int NKB = K2 / 32;
    __shared__ float WpL[10][32][33];
    __shared__ float eL[16][10];
    const int nc = blockIdx.x, kc = blockIdx.y, oc = blockIdx.z;
    const int tid = threadIdx.x;
    const int rb = kc * 32 + (SHIFT ? (kc >= 2 ? 2 : 1) : 0);
    const int ocol = oc * 32;
    const int n0 = nc * 16;

    for (int el = tid; el < 10 * 32 * 32; el += 256) {
        int d = el >> 10;
        int rem = el & 1023;
        int k = rem >> 5, o = rem & 31;
        WpL[d][k][o] = Wp[((size_t)d * KR + rb + k) * O + ocol + o];
    }
    if (tid < 160) eL[tid / 10][tid % 10] = E[(n0 + tid / 10) * 10 + tid % 10];
    __syncthreads();

    const int o2 = tid >> 3;
    const int kv = (tid & 7) * 4;
    const int o = ocol + o2;
    const int lane = ((kv >> 3) << 4) + (o & 15);
    const size_t fragbase =
        ((((size_t)0 * (O / 16) + (o >> 4)) * NKB + kc) * 64 + lane) * 8 + (kv & 7);
    const size_t nstride = (size_t)(O / 16) * NKB * 64 * 8;

    for (int ni = 0; ni < 16; ++ni) {
        float ev[10];
        #pragma unroll
        for (int d = 0; d < 10; ++d) ev[d] = eL[ni][d];
        u16 ph[4], pl[4];
        #pragma unroll
        for (int j = 0; j < 4; ++j) {
            float a = 0.f;
            #pragma unroll
            for (int d = 0; d < 10; ++d) a += ev[d] * WpL[d][kv + j][o2];
            u16 hb = f2b(a);
            ph[j] = hb;
            pl[j] = f2b(a - b2f(hb));
        }
        size_t off = fragbase + (size_t)(n0 + ni) * nstride;
        *(s16x4*)&oh[off] = *(s16x4*)ph;
        *(s16x4*)&ol[off] = *(s16x4*)pl;
    }
}

__global__ __launch_bounds__(256) void k_bias(const float* __restrict__ E, const float* __restrict__ gb0,
                                              const float* __restrict__ ub0, const float* __restrict__ gb1,
                                              const float* __restrict__ ub1, const float* __restrict__ gw0,
                                              const float* __restrict__ uw0,
                                              float* BG0, float* BU0, float* BG1, float* BU1,
                                              float* G0X, float* U0X) {
    __shared__ float e[10];
    int n = blockIdx.x, tid = threadIdx.x;
    if (tid < 10) e[tid] = E[n * 10 + tid];
    __syncthreads();
    if (tid < 128) {
        int o = tid;
        float a0 = 0, a1 = 0, a2 = 0, a3 = 0;
        #pragma unroll
        for (int d = 0; d < 10; ++d) {
            a0 += e[d] * gb0[d * 128 + o];
            a1 += e[d] * gb1[d * 128 + o];
            a2 += e[d] * gw0[((size_t)d * 130 + 0) * 128 + o];
            a3 += e[d] * gw0[((size_t)d * 130 + 65) * 128 + o];
        }
        BG0[n * 128 + o] = a0; BG1[n * 128 + o] = a1;
        G0X[n * 256 + o] = a2; G0X[n * 256 + 128 + o] = a3;
    } else if (tid < 192) {
        int o = tid - 128;
        float a0 = 0, a1 = 0, a2 = 0, a3 = 0;
        #pragma unroll
        for (int d = 0; d < 10; ++d) {
            a0 += e[d] * ub0[d * 64 + o];
            a1 += e[d] * ub1[d * 64 + o];
            a2 += e[d] * uw0[((size_t)d * 130 + 0) * 64 + o];
            a3 += e[d] * uw0[((size_t)d * 130 + 65) * 64 + o];
        }
        BU0[n * 64 + o] = a0; BU1[n * 64 + o] = a1;
        U0X[n * 128 + o] = a2; U0X[n * 128 + 64 + o] = a3;
    }
}

// ---------------- gmm shared + device body (round-17 verified, unchanged math) ----------------
struct GmmS {
    u16 As[2][64][72];
    u16 Bsh[2][2][64][32];
    u16 Bsl[2][2][64][32];
};

__device__ __forceinline__ void d_gmm(int by, int bx_, int tid,
                                      const u16* __restrict__ A, const u16* __restrict__ Bh,
                                      const u16* __restrict__ Bl, const float* __restrict__ dd,
                                      const float* __restrict__ lmax,
                                      u16* __restrict__ Ch, u16* __restrict__ Cl, int N, GmmS& S) {
    const int w = tid >> 6, l = tid & 63, lr = l & 15, lg = l >> 4;
    const int bm = by * 64, bn = bx_ * 64;
    const int am = tid >> 2, ak = (tid & 3) * 16;
    const int bk = tid >> 3, bn8 = (tid & 7) * 8;
    const int bx = (tid & 7) & 3;
    const int col = ((bk >> 3) ^ bx) * 8 + (bk & 7);
    f32x4 acc[4];
    #pragma unroll
    for (int a = 0; a < 4; ++a) acc[a] = (f32x4){0.f, 0.f, 0.f, 0.f};

    const int nl = w * 16 + lr;
    const int cc = (lg ^ ((nl >> 3) & 3)) * 8;
    const size_t arow = (size_t)(bm + am) * 512;

    s16x8 rA0, rA1, rBh[2], rBl[2];
    rA0 = *(const s16x8*)&A[arow + 0 + ak];
    rA1 = *(const s16x8*)&A[arow + 0 + ak + 8];
    #pragma unroll
    for (int hh = 0; hh < 2; ++hh) {
        rBh[hh] = *(const s16x8*)&Bh[(size_t)(0 + hh * 32 + bk) * N + bn + bn8];
        rBl[hh] = *(const s16x8*)&Bl[(size_t)(0 + hh * 32 + bk) * N + bn + bn8];
    }
    *(s16x8*)&S.As[0][am][ak]     = rA0;
    *(s16x8*)&S.As[0][am][ak + 8] = rA1;
    #pragma unroll
    for (int hh = 0; hh < 2; ++hh) {
        #pragma unroll
        for (int q = 0; q < 8; ++q) {
            S.Bsh[0][hh][bn8 + q][col] = ((const u16*)&rBh[hh])[q];
            S.Bsl[0][hh][bn8 + q][col] = ((const u16*)&rBl[hh])[q];
        }
    }
    __syncthreads();

    for (int k0 = 0; k0 < 512; k0 += 64) {
        const int cur = (k0 >> 6) & 1;
        const bool more = (k0 + 64 < 512);
        if (more) {
            rA0 = *(const s16x8*)&A[arow + k0 + 64 + ak];
            rA1 = *(const s16x8*)&A[arow + k0 + 64 + ak + 8];
            #pragma unroll
            for (int hh = 0; hh < 2; ++hh) {
                rBh[hh] = *(const s16x8*)&Bh[(size_t)(k0 + 64 + hh * 32 + bk) * N + bn + bn8];
                rBl[hh] = *(const s16x8*)&Bl[(size_t)(k0 + 64 + hh * 32 + bk) * N + bn + bn8];
            }
        }
        #pragma unroll
        for (int hh = 0; hh < 2; ++hh) {
            s16x8 bfh = *(const s16x8*)&S.Bsh[cur][hh][nl][cc];
            s16x8 bfl = *(const s16x8*)&S.Bsl[cur][hh][nl][cc];
            #pragma unroll
            for (int mf = 0; mf < 4; ++mf) {
                s16x8 afr = *(const s16x8*)&S.As[cur][mf * 16 + lr][hh * 32 + lg * 8];
                acc[mf] = __builtin_amdgcn_mfma_f32_16x16x32_bf16(afr, bfh, acc[mf], 0, 0, 0);
                acc[mf] = __builtin_amdgcn_mfma_f32_16x16x32_bf16(afr, bfl, acc[mf], 0, 0, 0);
            }
        }
        if (more) {
            const int nxt = cur ^ 1;
            *(s16x8*)&S.As[nxt][am][ak]     = rA0;
            *(s16x8*)&S.As[nxt][am][ak + 8] = rA1;
            #pragma unroll
            for (int hh = 0; hh < 2; ++hh) {
                #pragma unroll
                for (int q = 0; q < 8; ++q) {
                    S.Bsh[nxt][hh][bn8 + q][col] = ((const u16*)&rBh[hh])[q];
                    S.Bsl[nxt][hh][bn8 + q][col] = ((const u16*)&rBl[hh])[q];
                }
            }
        }
        __syncthreads();
    }
    const float lm = lmax[0], alpha = -2.f / lm;
    const int colg = bn + w * 16 + lr;
    #pragma unroll
    for (int mf = 0; mf < 4; ++mf) {
        #pragma unroll
        for (int i = 0; i < 4; ++i) {
            int rowg = bm + mf * 16 + lg * 4 + i;
            size_t off = (size_t)rowg * N + colg;
            float hval = b2f(Bh[off]) + b2f(Bl[off]);
            float beta = 2.f * dd[rowg] / lm - 1.f;
            float v = alpha * acc[mf][i] + beta * hval;
            u16 hb = f2b(v);
            Ch[off] = hb;
            Cl[off] = f2b(v - b2f(hb));
        }
    }
}

__global__ __launch_bounds__(256) void k_gmm(const u16* __restrict__ A, const u16* __restrict__ Bh,
                                             const u16* __restrict__ Bl, const float* __restrict__ dd,
                                             const float* __restrict__ lmax,
                                             u16* __restrict__ Ch, u16* __restrict__ Cl, int N) {
    __shared__ GmmS S;
    d_gmm(blockIdx.y, blockIdx.x, threadIdx.x, A, Bh, Bl, dd, lmax, Ch, Cl, N, S);
}

// ---------------- split-precision MFMA cell device body (round-16 verified) ----------------
struct CellP {
    const u16 *s0h, *s0l, *s1h, *s1l, *s2h, *s2l, *s3h, *s3l;
    const u16 *Wh, *Wl;
    const float *bias, *wx;
    const u16 *xsh, *xsl, *txh, *txl;
    const u16 *hph, *hpl;
    float* rbuf;
    u16 *oh, *ol;
    int xoff;
};
template <int K2, int O, bool GATE, bool RANK1>
__device__ __forceinline__ void d_cellp(int n, int tid, const CellP& p) {
    constexpr int NKB = K2 / 32;
    constexpr int MFW = (O == 128) ? 4 : 2;
    const int w = tid >> 6, l = tid & 63, lr = l & 15, lg = l >> 4;
    const int mbase = (O == 128) ? 0 : ((w >> 1) * 2);
    const int nbase = (O == 128) ? (2 * w) : ((w & 1) * 2);
    f32x4 acc[MFW][2];
    #pragma unroll
    for (int a = 0; a < MFW; ++a)
        #pragma unroll
        for (int c = 0; c < 2; ++c) acc[a][c] = (f32x4){0.f, 0.f, 0.f, 0.f};
    const size_t nb = (size_t)n * 4096;

    #pragma unroll
    for (int kb = 0; kb < NKB; ++kb) {
        const int sg = kb >> 1;
        const u16* sh = sg == 0 ? p.s0h : sg == 1 ? p.s1h : sg == 2 ? p.s2h : p.s3h;
        const u16* sl = sg == 0 ? p.s0l : sg == 1 ? p.s1l : sg == 2 ? p.s2l : p.s3l;
        const int koff = (kb & 1) * 32 + lg * 8;
        s16x8 bfh[2], bfl[2];
        #pragma unroll
        for (int nf = 0; nf < 2; ++nf) {
            size_t wof = ((((size_t)n * (O / 16) + (nbase + nf)) * NKB + kb) * 64 + l) * 8;
            bfh[nf] = *(const s16x8*)&p.Wh[wof];
            bfl[nf] = *(const s16x8*)&p.Wl[wof];
        }
        #pragma unroll
        for (int mf = 0; mf < MFW; ++mf) {
            int b = (mbase + mf) * 16 + lr;
            s16x8 ah = *(const s16x8*)&sh[nb + b * 64 + koff];
            s16x8 al = *(const s16x8*)&sl[nb + b * 64 + koff];
            #pragma unroll
            for (int nf = 0; nf < 2; ++nf) {
                acc[mf][nf] = __builtin_amdgcn_mfma_f32_16x16x32_bf16(ah, bfh[nf], acc[mf][nf], 0, 0, 0);
                acc[mf][nf] = __builtin_amdgcn_mfma_f32_16x16x32_bf16(ah, bfl[nf], acc[mf][nf], 0, 0, 0);
                acc[mf][nf] = __builtin_amdgcn_mfma_f32_16x16x32_bf16(al, bfh[nf], acc[mf][nf], 0, 0, 0);
            }
        }
    }

    const float* wxn = RANK1 ? (p.wx + (size_t)n * 2 * O) : p.wx;
    #pragma unroll
    for (int mf = 0; mf < MFW; ++mf) {
        #pragma unroll
        for (int i = 0; i < 4; ++i) {
            int b = (mbase + mf) * 16 + lg * 4 + i;
            float xf = 0.f, txf = 0.f;
            if (RANK1) {
                int idx = n * 768 + p.xoff + b;
                xf = b2f(p.xsh[idx]) + b2f(p.xsl[idx]);
                txf = b2f(p.txh[idx]) + b2f(p.txl[idx]);
            }
            #pragma unroll
            for (int nf = 0; nf < 2; ++nf) {
                int o = (nbase + nf) * 16 + lr;
                float s = acc[mf][nf][i] + p.bias[(size_t)n * O + o];
                if (RANK1) s += xf * wxn[o] + txf * wxn[O + o];
                size_t bo = nb + (size_t)b * 64;
                if (GATE) {
                    float v = 1.f / (1.f + expf(-s));
                    if (o < 64) {
                        float hp = b2f(p.hph[bo + o]) + b2f(p.hpl[bo + o]);
                        float zh = v * hp;
                        u16 hb = f2b(zh);
                        p.oh[bo + o] = hb;
                        p.ol[bo + o] = f2b(zh - b2f(hb));
                    } else {
                        p.rbuf[bo + (o - 64)] = v;
                    }
                } else {
                    float hc = tanhf(s);
                    float rv = p.rbuf[bo + o];
                    float hp = b2f(p.oh[bo + o]) + b2f(p.ol[bo + o]);
                    float hn = rv * hp + (1.f - rv) * hc;
                    u16 hb = f2b(hn);
                    p.oh[bo + o] = hb;
                    p.ol[bo + o] = f2b(hn - b2f(hb));
                }
            }
        }
    }
}

template <int K2, int O, bool GATE, bool RANK1>
__global__ __launch_bounds__(256) void k_cellp(CellP p) {
    d_cellp<K2, O, GATE, RANK1>(blockIdx.x, threadIdx.x, p);
}

// ---------------- ROUND 18: fused (gmm h1->th1) + (next step's g0 cell) ----------------
// The step-ending th1 gmm and the NEXT step's layer-0 gate are independent (gmm reads
// adj/h1, writes th1; g0 reads h0/th0, writes zh/rbuf — disjoint). One 1024-block
// dispatch runs both, removing 11 kernel boundaries from the serial chain.
struct FuseArgs {
    const u16* adjb; const u16 *h1h, *h1l; const float *dd, *lmax;
    u16 *th1h, *th1l;
    CellP cell;
};
__global__ __launch_bounds__(256) void k_fuse(FuseArgs a) {
    __shared__ GmmS S;
    const int bid = blockIdx.x;
    if (bid < 512) {
        d_gmm(bid >> 6, bid & 63, threadIdx.x, a.adjb, a.h1h, a.h1l, a.dd, a.lmax,
              a.th1h, a.th1l, 4096, S);
    } else {
        d_cellp<128, 128, true, true>(bid - 512, threadIdx.x, a.cell);
    }
}

// ---------------- end conv ----------------
__global__ __launch_bounds__(256) void k_conv(const u16* __restrict__ hh, const u16* __restrict__ hl,
                                              const float* __restrict__ cw, const float* __restrict__ cb,
                                              float* __restrict__ out) {
    int idx = blockIdx.x * 256 + threadIdx.x;
    int n = idx >> 6, b = idx & 63;
    float hv[64];
    #pragma unroll
    for (int q = 0; q < 8; ++q) {
        s16x8 vh = *(const s16x8*)&hh[(size_t)n * 4096 + b * 64 + q * 8];
        s16x8 vl = *(const s16x8*)&hl[(size_t)n * 4096 + b * 64 + q * 8];
        #pragma unroll
        for (int j = 0; j < 8; ++j) hv[q * 8 + j] = b2f((u16)vh[j]) + b2f((u16)vl[j]);
    }
    #pragma unroll
    for (int t = 0; t < TSEQ; ++t) {
        float s = cb[t];
        #pragma unroll
        for (int j = 0; j < 64; ++j) s += hv[j] * cw[t * 64 + j];
        out[((size_t)b * TSEQ + t) * NN + n] = s;
    }
}

// ---------------- launch ----------------
extern "C" void kernel_launch(void* const* d_in, const int* in_sizes, int n_in,
                              void* d_out, int out_size, void* d_ws, size_t ws_size,
                              hipStream_t stream) {
    const float* gts = (const float*)d_in[0];
    const float* gn  = (const float*)d_in[1];
    const float* E   = (const float*)d_in[2];
    const float* gw0 = (const float*)d_in[3];
    const float* gb0 = (const float*)d_in[4];
    const float* uw0 = (const float*)d_in[5];
    const float* ub0 = (const float*)d_in[6];
    const float* gw1 = (const float*)d_in[7];
    const float* gb1 = (const float*)d_in[8];
    const float* uw1 = (const float*)d_in[9];
    const float* ub1 = (const float*)d_in[10];
    const float* cw  = (const float*)d_in[11];
    const float* cb  = (const float*)d_in[12];
    float* out = (float*)d_out;
    char* ws = (char*)d_ws;

    if (ws_size < WS_BYTES) {
        k_marker<<<1, 64, 0, stream>>>(out, (float)(ws_size >> 20));
        return;
    }

    u16* adjb = (u16*)(ws + B_ADJ);
    float* dd = (float*)(ws + B_DD);
    float* nrm = (float*)(ws + B_NRM);
    float* lmax = (float*)(ws + B_LMAX);
    u16* xsh = (u16*)(ws + B_XSH);
    u16* xsl = (u16*)(ws + B_XSL);
    u16* txh = (u16*)(ws + B_TXH);
    u16* txl = (u16*)(ws + B_TXL);
    u16* h0h  = (u16*)(ws + B_ST + 0 * SZP);
    u16* h0l  = (u16*)(ws + B_ST + 1 * SZP);
    u16* h1h  = (u16*)(ws + B_ST + 2 * SZP);
    u16* h1l  = (u16*)(ws + B_ST + 3 * SZP);
    u16* th0h = (u16*)(ws + B_ST + 4 * SZP);
    u16* th0l = (u16*)(ws + B_ST + 5 * SZP);
    u16* th1h = (u16*)(ws + B_ST + 6 * SZP);
    u16* th1l = (u16*)(ws + B_ST + 7 * SZP);
    u16* zhh  = (u16*)(ws + B_ST + 8 * SZP);
    u16* zhl  = (u16*)(ws + B_ST + 9 * SZP);
    u16* tzh  = (u16*)(ws + B_ST + 10 * SZP);
    u16* tzl  = (u16*)(ws + B_ST + 11 * SZP);
    float* rbuf = (float*)(ws + B_RBUF);
    u16* G0TH = (u16*)(ws + B_G0TH);
    u16* G0TL = (u16*)(ws + B_G0TL);
    u16* U0TH = (u16*)(ws + B_U0TH);
    u16* U0TL = (u16*)(ws + B_U0TL);
    u16* G1TH = (u16*)(ws + B_G1TH);
    u16* G1TL = (u16*)(ws + B_G1TL);
    u16* U1TH = (u16*)(ws + B_U1TH);
    u16* U1TL = (u16*)(ws + B_U1TL);
    float* BG0 = (float*)(ws + B_BG0);
    float* BU0 = (float*)(ws + B_BU0);
    float* BG1 = (float*)(ws + B_BG1);
    float* BU1 = (float*)(ws + B_BU1);
    float* G0X = (float*)(ws + B_G0X);
    float* U0X = (float*)(ws + B_U0X);

    // REPLAY DETERMINISM: zero the ENTIRE used workspace every call (round-8 proven).
    hipMemsetAsync(ws, 0, WS_BYTES, stream);

    k_norm<<<2, 256, 0, stream>>>(E, nrm);
    k_adj<<<NN, 256, 0, stream>>>(E, gn, nrm, adjb, dd);
    k_dmax<<<1, 512, 0, stream>>>(dd, lmax);

    k_xs_bf<<<(NN * TSEQ * BB + 255) / 256, 256, 0, stream>>>(gts, xsh, xsl);
    k_gmm<<<dim3(TSEQ * BB / 64, 8), 256, 0, stream>>>(adjb, xsh, xsl, dd, lmax, txh, txl, TSEQ * BB);

    k_embed2<128, 128, true><<<dim3(32, 4, 4), 256, 0, stream>>>(E, gw0, G0TH, G0TL);
    k_embed2<128, 64, true><<<dim3(32, 4, 2), 256, 0, stream>>>(E, uw0, U0TH, U0TL);
    k_embed2<256, 128, false><<<dim3(32, 8, 4), 256, 0, stream>>>(E, gw1, G1TH, G1TL);
    k_embed2<256, 64, false><<<dim3(32, 8, 2), 256, 0, stream>>>(E, uw1, U1TH, U1TL);
    k_bias<<<512, 256, 0, stream>>>(E, gb0, ub0, gb1, ub1, gw0, uw0,
                                    BG0, BU0, BG1, BU1, G0X, U0X);

    const dim3 gmm_grid(BB * 64 / 64, 8);
    for (int t = 0; t < TSEQ; ++t) {
        int xoff = t * BB;
        // layer-0 gate: at t=0 standalone; for t>0 it was fused with the previous
        // step's th1 gmm (launched at the bottom of the previous iteration).
        if (t == 0) {
            CellP g0{h0h, h0l, th0h, th0l, nullptr, nullptr, nullptr, nullptr,
                     G0TH, G0TL, BG0, G0X, xsh, xsl, txh, txl, h0h, h0l, rbuf, zhh, zhl, xoff};
            k_cellp<128, 128, true, true><<<NN, 256, 0, stream>>>(g0);
        }
        k_gmm<<<gmm_grid, 256, 0, stream>>>(adjb, zhh, zhl, dd, lmax, tzh, tzl, 4096);
        CellP u0{zhh, zhl, tzh, tzl, nullptr, nullptr, nullptr, nullptr,
                 U0TH, U0TL, BU0, U0X, xsh, xsl, txh, txl, nullptr, nullptr, rbuf, h0h, h0l, xoff};
        k_cellp<128, 64, false, true><<<NN, 256, 0, stream>>>(u0);
        k_gmm<<<gmm_grid, 256, 0, stream>>>(adjb, h0h, h0l, dd, lmax, th0h, th0l, 4096);
        CellP g1{h0h, h0l, h1h, h1l, th0h, th0l, th1h, th1l,
                 G1TH, G1TL, BG1, nullptr, nullptr, nullptr, nullptr, nullptr, h1h, h1l, rbuf, zhh, zhl, 0};
        k_cellp<256, 128, true, false><<<NN, 256, 0, stream>>>(g1);
        k_gmm<<<gmm_grid, 256, 0, stream>>>(adjb, zhh, zhl, dd, lmax, tzh, tzl, 4096);
        CellP u1{h0h, h0l, zhh, zhl, th0h, th0l, tzh, tzl,
                 U1TH, U1TL, BU1, nullptr, nullptr, nullptr, nullptr, nullptr, nullptr, nullptr, rbuf, h1h, h1l, 0};
        k_cellp<256, 64, false, false><<<NN, 256, 0, stream>>>(u1);
        if (t + 1 < TSEQ) {
            // fused: th1 gmm + next step's g0 cell (independent; see header comment)
            CellP g0n{h0h, h0l, th0h, th0l, nullptr, nullptr, nullptr, nullptr,
                      G0TH, G0TL, BG0, G0X, xsh, xsl, txh, txl, h0h, h0l, rbuf, zhh, zhl, (t + 1) * BB};
            FuseArgs fa{adjb, h1h, h1l, dd, lmax, th1h, th1l, g0n};
            k_fuse<<<1024, 256, 0, stream>>>(fa);
        }
    }

    k_conv<<<NN * BB / 256, 256, 0, stream>>>(h1h, h1l, cw, cb, out);
}

// Round 19
// 1737.774 us; speedup vs baseline: 1.1852x; 1.0729x over previous
//
#include <hip/hip_runtime.h>
#include <math.h>

#define NN 512
#define TSEQ 12
#define BB 64

typedef unsigned short u16;
typedef short s16x4 __attribute__((ext_vector_type(4)));
typedef short s16x8 __attribute__((ext_vector_type(8)));
typedef float f32x4 __attribute__((ext_vector_type(4)));

__device__ __forceinline__ float b2f(u16 h) { return __uint_as_float(((unsigned)h) << 16); }
__device__ __forceinline__ u16 f2b(float f) {
    unsigned u = __float_as_uint(f);
    return (u16)((u + 0x7FFFu + ((u >> 16) & 1u)) >> 16);
}

// ---------------- workspace layout (bytes) ----------------
constexpr size_t SZP    = (size_t)512 * 4096 * 2;   // one state plane (4 MB)
constexpr size_t B_ADJ  = 0;
constexpr size_t B_DD   = B_ADJ + 524288;
constexpr size_t B_NRM  = B_DD + 2048;
constexpr size_t B_LMAX = B_NRM + 2048;
constexpr size_t B_XSH  = B_LMAX + 256;
constexpr size_t B_XSL  = B_XSH + 786432;
constexpr size_t B_TXH  = B_XSL + 786432;
constexpr size_t B_TXL  = B_TXH + 786432;
constexpr size_t B_ST   = B_TXL + 786432;           // 12 planes
constexpr size_t B_RBUF = B_ST + 12 * SZP;
constexpr size_t B_G0TH = B_RBUF + 8388608;
constexpr size_t B_G0TL = B_G0TH + 16777216;
constexpr size_t B_U0TH = B_G0TL + 16777216;
constexpr size_t B_U0TL = B_U0TH + 8388608;
constexpr size_t B_G1TH = B_U0TL + 8388608;
constexpr size_t B_G1TL = B_G1TH + 33554432;
constexpr size_t B_U1TH = B_G1TL + 33554432;
constexpr size_t B_U1TL = B_U1TH + 16777216;
constexpr size_t B_BG0  = B_U1TL + 16777216;
constexpr size_t B_BU0  = B_BG0 + 262144;
constexpr size_t B_BG1  = B_BU0 + 131072;
constexpr size_t B_BU1  = B_BG1 + 262144;
constexpr size_t B_G0X  = B_BU1 + 131072;
constexpr size_t B_U0X  = B_G0X + 524288;
constexpr size_t WS_BYTES = B_U0X + 262144;         // ~205 MiB

// ---------------- setup kernels ----------------

__global__ void k_marker(float* out, float v) { out[threadIdx.x] = v; }

__global__ void k_norm(const float* __restrict__ E, float* __restrict__ nrm) {
    int n = blockIdx.x * blockDim.x + threadIdx.x;
    if (n < NN) {
        float s = 0.f;
        #pragma unroll
        for (int q = 0; q < 10; ++q) { float e = E[n * 10 + q]; s += e * e; }
        nrm[n] = sqrtf(s);
    }
}

__global__ __launch_bounds__(256) void k_adj(const float* __restrict__ E, const float* __restrict__ gn,
                                             const float* __restrict__ nrm, u16* __restrict__ adjb,
                                             float* __restrict__ dd) {
    __shared__ float En[10];
    __shared__ float red[256];
    int n = blockIdx.x, tid = threadIdx.x;
    if (tid < 10) En[tid] = E[n * 10 + tid];
    __syncthreads();
    float nn = nrm[n];
    float cnt = 0.f;
    for (int m = tid; m < NN; m += 256) {
        float dot = 0.f;
        #pragma unroll
        for (int q = 0; q < 10; ++q) dot += En[q] * E[m * 10 + q];
        float lg = dot / (nn * nrm[m]);
        lg = (lg + 1.f) * 0.5f;
        float g0 = gn[((size_t)n * NN + m) * 2 + 0];
        float g1 = gn[((size_t)n * NN + m) * 2 + 1];
        bool a = ((lg + g0) >= (1.f - lg + g1) && (m != n));
        adjb[(size_t)n * NN + m] = a ? 0x3F80 : 0;
        cnt += a ? 1.f : 0.f;
    }
    red[tid] = cnt;
    __syncthreads();
    for (int s = 128; s > 0; s >>= 1) { if (tid < s) red[tid] += red[tid + s]; __syncthreads(); }
    if (tid == 0) dd[n] = red[0];
}

__global__ void k_dmax(const float* __restrict__ dd, float* __restrict__ lmax) {
    __shared__ float red[512];
    int t = threadIdx.x;
    red[t] = dd[t];
    __syncthreads();
    for (int s = 256; s > 0; s >>= 1) { if (t < s) red[t] = fmaxf(red[t], red[t + s]); __syncthreads(); }
    if (t == 0) lmax[0] = red[0] + (red[0] > 0.f ? 1.f : 0.f);
}

__global__ __launch_bounds__(256) void k_xs_bf(const float* __restrict__ gts, u16* __restrict__ xh,
                                               u16* __restrict__ xl) {
    int idx = blockIdx.x * 256 + threadIdx.x;
    if (idx >= NN * TSEQ * BB) return;
    int n = idx / (TSEQ * BB);
    int rem = idx - n * (TSEQ * BB);
    int t = rem >> 6, b = rem & 63;
    float v = gts[((size_t)b * NN + n) * TSEQ + t];
    u16 hb = f2b(v);
    xh[idx] = hb;
    xl[idx] = f2b(v - b2f(hb));
}

// ---------------- embed v3 (round-16): Wp in LDS + fragment-major output ----------------
template <int K2, int O, bool SHIFT>
__global__ __launch_bounds__(256) void k_embed2(const float* __restrict__ E, const float* __restrict__ Wp,
                                                u16* __restrict__ oh, u16* __restrict__ ol) {
    constexpr int KR = SHIFT ? 130 : K2;
    constexpr int NKB = K2 / 32;
    __shared__ float WpL[10][32][33];
    __shared__ float eL[16][10];
    const int nc = blockIdx.x, kc = blockIdx.y, oc = blockIdx.z;
    const int tid = threadIdx.x;
    const int rb = kc * 32 + (SHIFT ? (kc >= 2 ? 2 : 1) : 0);
    const int ocol = oc * 32;
    const int n0 = nc * 16;

    for (int el = tid; el < 10 * 32 * 32; el += 256) {
        int d = el >> 10;
        int rem = el & 1023;
        int k = rem >> 5, o = rem & 31;
        WpL[d][k][o] = Wp[((size_t)d * KR + rb + k) * O + ocol + o];
    }
    if (tid < 160) eL[tid / 10][tid % 10] = E[(n0 + tid / 10) * 10 + tid % 10];
    __syncthreads();

    const int o2 = tid >> 3;
    const int kv = (tid & 7) * 4;
    const int o = ocol + o2;
    const int lane = ((kv >> 3) << 4) + (o & 15);
    const size_t fragbase =
        ((((size_t)0 * (O / 16) + (o >> 4)) * NKB + kc) * 64 + lane) * 8 + (kv & 7);
    const size_t nstride = (size_t)(O / 16) * NKB * 64 * 8;

    for (int ni = 0; ni < 16; ++ni) {
        float ev[10];
        #pragma unroll
        for (int d = 0; d < 10; ++d) ev[d] = eL[ni][d];
        u16 ph[4], pl[4];
        #pragma unroll
        for (int j = 0; j < 4; ++j) {
            float a = 0.f;
            #pragma unroll
            for (int d = 0; d < 10; ++d) a += ev[d] * WpL[d][kv + j][o2];
            u16 hb = f2b(a);
            ph[j] = hb;
            pl[j] = f2b(a - b2f(hb));
        }
        size_t off = fragbase + (size_t)(n0 + ni) * nstride;
        *(s16x4*)&oh[off] = *(s16x4*)ph;
        *(s16x4*)&ol[off] = *(s16x4*)pl;
    }
}

__global__ __launch_bounds__(256) void k_bias(const float* __restrict__ E, const float* __restrict__ gb0,
                                              const float* __restrict__ ub0, const float* __restrict__ gb1,
                                              const float* __restrict__ ub1, const float* __restrict__ gw0,
                                              const float* __restrict__ uw0,
                                              float* BG0, float* BU0, float* BG1, float* BU1,
                                              float* G0X, float* U0X) {
    __shared__ float e[10];
    int n = blockIdx.x, tid = threadIdx.x;
    if (tid < 10) e[tid] = E[n * 10 + tid];
    __syncthreads();
    if (tid < 128) {
        int o = tid;
        float a0 = 0, a1 = 0, a2 = 0, a3 = 0;
        #pragma unroll
        for (int d = 0; d < 10; ++d) {
            a0 += e[d] * gb0[d * 128 + o];
            a1 += e[d] * gb1[d * 128 + o];
            a2 += e[d] * gw0[((size_t)d * 130 + 0) * 128 + o];
            a3 += e[d] * gw0[((size_t)d * 130 + 65) * 128 + o];
        }
        BG0[n * 128 + o] = a0; BG1[n * 128 + o] = a1;
        G0X[n * 256 + o] = a2; G0X[n * 256 + 128 + o] = a3;
    } else if (tid < 192) {
        int o = tid - 128;
        float a0 = 0, a1 = 0, a2 = 0, a3 = 0;
        #pragma unroll
        for (int d = 0; d < 10; ++d) {
            a0 += e[d] * ub0[d * 64 + o];
            a1 += e[d] * ub1[d * 64 + o];
            a2 += e[d] * uw0[((size_t)d * 130 + 0) * 64 + o];
            a3 += e[d] * uw0[((size_t)d * 130 + 65) * 64 + o];
        }
        BU0[n * 64 + o] = a0; BU1[n * 64 + o] = a1;
        U0X[n * 128 + o] = a2; U0X[n * 128 + 64 + o] = a3;
    }
}

// ---------------- gmm shared + device body (round-17 verified) ----------------
struct GmmS {
    u16 As[2][64][72];
    u16 Bsh[2][2][64][32];
    u16 Bsl[2][2][64][32];
};

__device__ __forceinline__ void d_gmm(int by, int bx_, int tid,
                                      const u16* __restrict__ A, const u16* __restrict__ Bh,
                                      const u16* __restrict__ Bl, const float* __restrict__ dd,
                                      const float* __restrict__ lmax,
                                      u16* __restrict__ Ch, u16* __restrict__ Cl, int N, GmmS& S) {
    const int w = tid >> 6, l = tid & 63, lr = l & 15, lg = l >> 4;
    const int bm = by * 64, bn = bx_ * 64;
    const int am = tid >> 2, ak = (tid & 3) * 16;
    const int bk = tid >> 3, bn8 = (tid & 7) * 8;
    const int bx = (tid & 7) & 3;
    const int col = ((bk >> 3) ^ bx) * 8 + (bk & 7);
    f32x4 acc[4];
    #pragma unroll
    for (int a = 0; a < 4; ++a) acc[a] = (f32x4){0.f, 0.f, 0.f, 0.f};

    const int nl = w * 16 + lr;
    const int cc = (lg ^ ((nl >> 3) & 3)) * 8;
    const size_t arow = (size_t)(bm + am) * 512;

    s16x8 rA0, rA1, rBh[2], rBl[2];
    rA0 = *(const s16x8*)&A[arow + 0 + ak];
    rA1 = *(const s16x8*)&A[arow + 0 + ak + 8];
    #pragma unroll
    for (int hh = 0; hh < 2; ++hh) {
        rBh[hh] = *(const s16x8*)&Bh[(size_t)(0 + hh * 32 + bk) * N + bn + bn8];
        rBl[hh] = *(const s16x8*)&Bl[(size_t)(0 + hh * 32 + bk) * N + bn + bn8];
    }
    *(s16x8*)&S.As[0][am][ak]     = rA0;
    *(s16x8*)&S.As[0][am][ak + 8] = rA1;
    #pragma unroll
    for (int hh = 0; hh < 2; ++hh) {
        #pragma unroll
        for (int q = 0; q < 8; ++q) {
            S.Bsh[0][hh][bn8 + q][col] = ((const u16*)&rBh[hh])[q];
            S.Bsl[0][hh][bn8 + q][col] = ((const u16*)&rBl[hh])[q];
        }
    }
    __syncthreads();

    for (int k0 = 0; k0 < 512; k0 += 64) {
        const int cur = (k0 >> 6) & 1;
        const bool more = (k0 + 64 < 512);
        if (more) {
            rA0 = *(const s16x8*)&A[arow + k0 + 64 + ak];
            rA1 = *(const s16x8*)&A[arow + k0 + 64 + ak + 8];
            #pragma unroll
            for (int hh = 0; hh < 2; ++hh) {
                rBh[hh] = *(const s16x8*)&Bh[(size_t)(k0 + 64 + hh * 32 + bk) * N + bn + bn8];
                rBl[hh] = *(const s16x8*)&Bl[(size_t)(k0 + 64 + hh * 32 + bk) * N + bn + bn8];
            }
        }
        #pragma unroll
        for (int hh = 0; hh < 2; ++hh) {
            s16x8 bfh = *(const s16x8*)&S.Bsh[cur][hh][nl][cc];
            s16x8 bfl = *(const s16x8*)&S.Bsl[cur][hh][nl][cc];
            #pragma unroll
            for (int mf = 0; mf < 4; ++mf) {
                s16x8 afr = *(const s16x8*)&S.As[cur][mf * 16 + lr][hh * 32 + lg * 8];
                acc[mf] = __builtin_amdgcn_mfma_f32_16x16x32_bf16(afr, bfh, acc[mf], 0, 0, 0);
                acc[mf] = __builtin_amdgcn_mfma_f32_16x16x32_bf16(afr, bfl, acc[mf], 0, 0, 0);
            }
        }
        if (more) {
            const int nxt = cur ^ 1;
            *(s16x8*)&S.As[nxt][am][ak]     = rA0;
            *(s16x8*)&S.As[nxt][am][ak + 8] = rA1;
            #pragma unroll
            for (int hh = 0; hh < 2; ++hh) {
                #pragma unroll
                for (int q = 0; q < 8; ++q) {
                    S.Bsh[nxt][hh][bn8 + q][col] = ((const u16*)&rBh[hh])[q];
                    S.Bsl[nxt][hh][bn8 + q][col] = ((const u16*)&rBl[hh])[q];
                }
            }
        }
        __syncthreads();
    }
    const float lm = lmax[0], alpha = -2.f / lm;
    const int colg = bn + w * 16 + lr;
    #pragma unroll
    for (int mf = 0; mf < 4; ++mf) {
        #pragma unroll
        for (int i = 0; i < 4; ++i) {
            int rowg = bm + mf * 16 + lg * 4 + i;
            size_t off = (size_t)rowg * N + colg;
            float hval = b2f(Bh[off]) + b2f(Bl[off]);
            float beta = 2.f * dd[rowg] / lm - 1.f;
            float v = alpha * acc[mf][i] + beta * hval;
            u16 hb = f2b(v);
            Ch[off] = hb;
            Cl[off] = f2b(v - b2f(hb));
        }
    }
}

__global__ __launch_bounds__(256) void k_gmm(const u16* __restrict__ A, const u16* __restrict__ Bh,
                                             const u16* __restrict__ Bl, const float* __restrict__ dd,
                                             const float* __restrict__ lmax,
                                             u16* __restrict__ Ch, u16* __restrict__ Cl, int N) {
    __shared__ GmmS S;
    d_gmm(blockIdx.y, blockIdx.x, threadIdx.x, A, Bh, Bl, dd, lmax, Ch, Cl, N, S);
}

// ---------------- split-precision MFMA cell (round-16 verified bodies) ----------------
struct CellP {
    const u16 *s0h, *s0l, *s1h, *s1l, *s2h, *s2l, *s3h, *s3l;
    const u16 *Wh, *Wl;
    const float *bias, *wx;
    const u16 *xsh, *xsl, *txh, *txl;
    const u16 *hph, *hpl;
    float* rbuf;
    u16 *oh, *ol;
    int xoff;
};

// UPDATE cell (O=64), unchanged from round 18
template <int K2, bool RANK1>
__device__ __forceinline__ void d_cellu(int n, int tid, const CellP& p) {
    constexpr int NKB = K2 / 32;
    const int w = tid >> 6, l = tid & 63, lr = l & 15, lg = l >> 4;
    const int mbase = (w >> 1) * 2;
    const int nbase = (w & 1) * 2;
    f32x4 acc[2][2];
    #pragma unroll
    for (int a = 0; a < 2; ++a)
        #pragma unroll
        for (int c = 0; c < 2; ++c) acc[a][c] = (f32x4){0.f, 0.f, 0.f, 0.f};
    const size_t nb = (size_t)n * 4096;

    #pragma unroll
    for (int kb = 0; kb < NKB; ++kb) {
        const int sg = kb >> 1;
        const u16* sh = sg == 0 ? p.s0h : sg == 1 ? p.s1h : sg == 2 ? p.s2h : p.s3h;
        const u16* sl = sg == 0 ? p.s0l : sg == 1 ? p.s1l : sg == 2 ? p.s2l : p.s3l;
        const int koff = (kb & 1) * 32 + lg * 8;
        s16x8 bfh[2], bfl[2];
        #pragma unroll
        for (int nf = 0; nf < 2; ++nf) {
            size_t wof = ((((size_t)n * 4 + (nbase + nf)) * NKB + kb) * 64 + l) * 8;
            bfh[nf] = *(const s16x8*)&p.Wh[wof];
            bfl[nf] = *(const s16x8*)&p.Wl[wof];
        }
        #pragma unroll
        for (int mf = 0; mf < 2; ++mf) {
            int b = (mbase + mf) * 16 + lr;
            s16x8 ah = *(const s16x8*)&sh[nb + b * 64 + koff];
            s16x8 al = *(const s16x8*)&sl[nb + b * 64 + koff];
            #pragma unroll
            for (int nf = 0; nf < 2; ++nf) {
                acc[mf][nf] = __builtin_amdgcn_mfma_f32_16x16x32_bf16(ah, bfh[nf], acc[mf][nf], 0, 0, 0);
                acc[mf][nf] = __builtin_amdgcn_mfma_f32_16x16x32_bf16(ah, bfl[nf], acc[mf][nf], 0, 0, 0);
                acc[mf][nf] = __builtin_amdgcn_mfma_f32_16x16x32_bf16(al, bfh[nf], acc[mf][nf], 0, 0, 0);
            }
        }
    }

    const float* wxn = RANK1 ? (p.wx + (size_t)n * 2 * 64) : p.wx;
    #pragma unroll
    for (int mf = 0; mf < 2; ++mf) {
        #pragma unroll
        for (int i = 0; i < 4; ++i) {
            int b = (mbase + mf) * 16 + lg * 4 + i;
            float xf = 0.f, txf = 0.f;
            if (RANK1) {
                int idx = n * 768 + p.xoff + b;
                xf = b2f(p.xsh[idx]) + b2f(p.xsl[idx]);
                txf = b2f(p.txh[idx]) + b2f(p.txl[idx]);
            }
            #pragma unroll
            for (int nf = 0; nf < 2; ++nf) {
                int o = (nbase + nf) * 16 + lr;
                float s = acc[mf][nf][i] + p.bias[(size_t)n * 64 + o];
                if (RANK1) s += xf * wxn[o] + txf * wxn[64 + o];
                size_t bo = nb + (size_t)b * 64;
                float hc = tanhf(s);
                float rv = p.rbuf[bo + o];
                float hp = b2f(p.oh[bo + o]) + b2f(p.ol[bo + o]);
                float hn = rv * hp + (1.f - rv) * hc;
                u16 hb = f2b(hn);
                p.oh[bo + o] = hb;
                p.ol[bo + o] = f2b(hn - b2f(hb));
            }
        }
    }
}
template <int K2, bool RANK1>
__global__ __launch_bounds__(256) void k_cellu(CellP p) {
    d_cellu<K2, RANK1>(blockIdx.x, threadIdx.x, p);
}

// ROUND 19: GATE cell split by o-half — block = (node, ohalf), 1024 blocks (4/CU).
// Each block computes 64 batches x 64 outputs in [ohalf*64, ohalf*64+64); streams half
// the weight bytes. Per-output K/MFMA order identical to round 18 -> bit-identical.
// The o<64 epilogue branch becomes block-uniform.
template <int K2, bool RANK1>
__device__ __forceinline__ void d_cellg2(int n, int ohalf, int tid, const CellP& p) {
    constexpr int NKB = K2 / 32;
    const int w = tid >> 6, l = tid & 63, lr = l & 15, lg = l >> 4;
    const int mbase = (w >> 1) * 2;
    const int nbase = (w & 1) * 2;
    f32x4 acc[2][2];
    #pragma unroll
    for (int a = 0; a < 2; ++a)
        #pragma unroll
        for (int c = 0; c < 2; ++c) acc[a][c] = (f32x4){0.f, 0.f, 0.f, 0.f};
    const size_t nb = (size_t)n * 4096;

    #pragma unroll
    for (int kb = 0; kb < NKB; ++kb) {
        const int sg = kb >> 1;
        const u16* sh = sg == 0 ? p.s0h : sg == 1 ? p.s1h : sg == 2 ? p.s2h : p.s3h;
        const u16* sl = sg == 0 ? p.s0l : sg == 1 ? p.s1l : sg == 2 ? p.s2l : p.s3l;
        const int koff = (kb & 1) * 32 + lg * 8;
        s16x8 bfh[2], bfl[2];
        #pragma unroll
        for (int nf = 0; nf < 2; ++nf) {
            // global fragment index within O=128: ohalf*4 + nbase + nf (of 8)
            size_t wof = ((((size_t)n * 8 + ohalf * 4 + nbase + nf) * NKB + kb) * 64 + l) * 8;
            bfh[nf] = *(const s16x8*)&p.Wh[wof];
            bfl[nf] = *(const s16x8*)&p.Wl[wof];
        }
        #pragma unroll
        for (int mf = 0; mf < 2; ++mf) {
            int b = (mbase + mf) * 16 + lr;
            s16x8 ah = *(const s16x8*)&sh[nb + b * 64 + koff];
            s16x8 al = *(const s16x8*)&sl[nb + b * 64 + koff];
            #pragma unroll
            for (int nf = 0; nf < 2; ++nf) {
                acc[mf][nf] = __builtin_amdgcn_mfma_f32_16x16x32_bf16(ah, bfh[nf], acc[mf][nf], 0, 0, 0);
                acc[mf][nf] = __builtin_amdgcn_mfma_f32_16x16x32_bf16(ah, bfl[nf], acc[mf][nf], 0, 0, 0);
                acc[mf][nf] = __builtin_amdgcn_mfma_f32_16x16x32_bf16(al, bfh[nf], acc[mf][nf], 0, 0, 0);
            }
        }
    }

    const float* wxn = RANK1 ? (p.wx + (size_t)n * 2 * 128) : p.wx;
    #pragma unroll
    for (int mf = 0; mf < 2; ++mf) {
        #pragma unroll
        for (int i = 0; i < 4; ++i) {
            int b = (mbase + mf) * 16 + lg * 4 + i;
            float xf = 0.f, txf = 0.f;
            if (RANK1) {
                int idx = n * 768 + p.xoff + b;
                xf = b2f(p.xsh[idx]) + b2f(p.xsl[idx]);
                txf = b2f(p.txh[idx]) + b2f(p.txl[idx]);
            }
            #pragma unroll
            for (int nf = 0; nf < 2; ++nf) {
                int o = ohalf * 64 + (nbase + nf) * 16 + lr;
                float s = acc[mf][nf][i] + p.bias[(size_t)n * 128 + o];
                if (RANK1) s += xf * wxn[o] + txf * wxn[128 + o];
                size_t bo = nb + (size_t)b * 64;
                float v = 1.f / (1.f + expf(-s));
                if (o < 64) {                      // block-uniform (ohalf==0)
                    float hp = b2f(p.hph[bo + o]) + b2f(p.hpl[bo + o]);
                    float zh = v * hp;
                    u16 hb = f2b(zh);
                    p.oh[bo + o] = hb;
                    p.ol[bo + o] = f2b(zh - b2f(hb));
                } else {
                    p.rbuf[bo + (o - 64)] = v;
                }
            }
        }
    }
}
template <int K2, bool RANK1>
__global__ __launch_bounds__(256) void k_cellg2(CellP p) {
    d_cellg2<K2, RANK1>(blockIdx.x, blockIdx.y, threadIdx.x, p);
}

// ---------------- fused (gmm h1->th1) + (next step's split g0 cell) ----------------
struct FuseArgs {
    const u16* adjb; const u16 *h1h, *h1l; const float *dd, *lmax;
    u16 *th1h, *th1l;
    CellP cell;
};
__global__ __launch_bounds__(256) void k_fuse(FuseArgs a) {
    __shared__ GmmS S;
    const int bid = blockIdx.x;
    if (bid < 512) {
        d_gmm(bid >> 6, bid & 63, threadIdx.x, a.adjb, a.h1h, a.h1l, a.dd, a.lmax,
              a.th1h, a.th1l, 4096, S);
    } else {
        const int cb = bid - 512;
        d_cellg2<128, true>(cb >> 1, cb & 1, threadIdx.x, a.cell);
    }
}

// ---------------- end conv ----------------
__global__ __launch_bounds__(256) void k_conv(const u16* __restrict__ hh, const u16* __restrict__ hl,
                                              const float* __restrict__ cw, const float* __restrict__ cb,
                                              float* __restrict__ out) {
    int idx = blockIdx.x * 256 + threadIdx.x;
    int n = idx >> 6, b = idx & 63;
    float hv[64];
    #pragma unroll
    for (int q = 0; q < 8; ++q) {
        s16x8 vh = *(const s16x8*)&hh[(size_t)n * 4096 + b * 64 + q * 8];
        s16x8 vl = *(const s16x8*)&hl[(size_t)n * 4096 + b * 64 + q * 8];
        #pragma unroll
        for (int j = 0; j < 8; ++j) hv[q * 8 + j] = b2f((u16)vh[j]) + b2f((u16)vl[j]);
    }
    #pragma unroll
    for (int t = 0; t < TSEQ; ++t) {
        float s = cb[t];
        #pragma unroll
        for (int j = 0; j < 64; ++j) s += hv[j] * cw[t * 64 + j];
        out[((size_t)b * TSEQ + t) * NN + n] = s;
    }
}

// ---------------- launch ----------------
extern "C" void kernel_launch(void* const* d_in, const int* in_sizes, int n_in,
                              void* d_out, int out_size, void* d_ws, size_t ws_size,
                              hipStream_t stream) {
    const float* gts = (const float*)d_in[0];
    const float* gn  = (const float*)d_in[1];
    const float* E   = (const float*)d_in[2];
    const float* gw0 = (const float*)d_in[3];
    const float* gb0 = (const float*)d_in[4];
    const float* uw0 = (const float*)d_in[5];
    const float* ub0 = (const float*)d_in[6];
    const float* gw1 = (const float*)d_in[7];
    const float* gb1 = (const float*)d_in[8];
    const float* uw1 = (const float*)d_in[9];
    const float* ub1 = (const float*)d_in[10];
    const float* cw  = (const float*)d_in[11];
    const float* cb  = (const float*)d_in[12];
    float* out = (float*)d_out;
    char* ws = (char*)d_ws;

    if (ws_size < WS_BYTES) {
        k_marker<<<1, 64, 0, stream>>>(out, (float)(ws_size >> 20));
        return;
    }

    u16* adjb = (u16*)(ws + B_ADJ);
    float* dd = (float*)(ws + B_DD);
    float* nrm = (float*)(ws + B_NRM);
    float* lmax = (float*)(ws + B_LMAX);
    u16* xsh = (u16*)(ws + B_XSH);
    u16* xsl = (u16*)(ws + B_XSL);
    u16* txh = (u16*)(ws + B_TXH);
    u16* txl = (u16*)(ws + B_TXL);
    u16* h0h  = (u16*)(ws + B_ST + 0 * SZP);
    u16* h0l  = (u16*)(ws + B_ST + 1 * SZP);
    u16* h1h  = (u16*)(ws + B_ST + 2 * SZP);
    u16* h1l  = (u16*)(ws + B_ST + 3 * SZP);
    u16* th0h = (u16*)(ws + B_ST + 4 * SZP);
    u16* th0l = (u16*)(ws + B_ST + 5 * SZP);
    u16* th1h = (u16*)(ws + B_ST + 6 * SZP);
    u16* th1l = (u16*)(ws + B_ST + 7 * SZP);
    u16* zhh  = (u16*)(ws + B_ST + 8 * SZP);
    u16* zhl  = (u16*)(ws + B_ST + 9 * SZP);
    u16* tzh  = (u16*)(ws + B_ST + 10 * SZP);
    u16* tzl  = (u16*)(ws + B_ST + 11 * SZP);
    float* rbuf = (float*)(ws + B_RBUF);
    u16* G0TH = (u16*)(ws + B_G0TH);
    u16* G0TL = (u16*)(ws + B_G0TL);
    u16* U0TH = (u16*)(ws + B_U0TH);
    u16* U0TL = (u16*)(ws + B_U0TL);
    u16* G1TH = (u16*)(ws + B_G1TH);
    u16* G1TL = (u16*)(ws + B_G1TL);
    u16* U1TH = (u16*)(ws + B_U1TH);
    u16* U1TL = (u16*)(ws + B_U1TL);
    float* BG0 = (float*)(ws + B_BG0);
    float* BU0 = (float*)(ws + B_BU0);
    float* BG1 = (float*)(ws + B_BG1);
    float* BU1 = (float*)(ws + B_BU1);
    float* G0X = (float*)(ws + B_G0X);
    float* U0X = (float*)(ws + B_U0X);

    // REPLAY DETERMINISM: zero the ENTIRE used workspace every call (round-8 proven).
    hipMemsetAsync(ws, 0, WS_BYTES, stream);

    k_norm<<<2, 256, 0, stream>>>(E, nrm);
    k_adj<<<NN, 256, 0, stream>>>(E, gn, nrm, adjb, dd);
    k_dmax<<<1, 512, 0, stream>>>(dd, lmax);

    k_xs_bf<<<(NN * TSEQ * BB + 255) / 256, 256, 0, stream>>>(gts, xsh, xsl);
    k_gmm<<<dim3(TSEQ * BB / 64, 8), 256, 0, stream>>>(adjb, xsh, xsl, dd, lmax, txh, txl, TSEQ * BB);

    k_embed2<128, 128, true><<<dim3(32, 4, 4), 256, 0, stream>>>(E, gw0, G0TH, G0TL);
    k_embed2<128, 64, true><<<dim3(32, 4, 2), 256, 0, stream>>>(E, uw0, U0TH, U0TL);
    k_embed2<256, 128, false><<<dim3(32, 8, 4), 256, 0, stream>>>(E, gw1, G1TH, G1TL);
    k_embed2<256, 64, false><<<dim3(32, 8, 2), 256, 0, stream>>>(E, uw1, U1TH, U1TL);
    k_bias<<<512, 256, 0, stream>>>(E, gb0, ub0, gb1, ub1, gw0, uw0,
                                    BG0, BU0, BG1, BU1, G0X, U0X);

    const dim3 gmm_grid(BB * 64 / 64, 8);
    for (int t = 0; t < TSEQ; ++t) {
        int xoff = t * BB;
        if (t == 0) {
            CellP g0{h0h, h0l, th0h, th0l, nullptr, nullptr, nullptr, nullptr,
                     G0TH, G0TL, BG0, G0X, xsh, xsl, txh, txl, h0h, h0l, rbuf, zhh, zhl, xoff};
            k_cellg2<128, true><<<dim3(512, 2), 256, 0, stream>>>(g0);
        }
        k_gmm<<<gmm_grid, 256, 0, stream>>>(adjb, zhh, zhl, dd, lmax, tzh, tzl, 4096);
        CellP u0{zhh, zhl, tzh, tzl, nullptr, nullptr, nullptr, nullptr,
                 U0TH, U0TL, BU0, U0X, xsh, xsl, txh, txl, nullptr, nullptr, rbuf, h0h, h0l, xoff};
        k_cellu<128, true><<<NN, 256, 0, stream>>>(u0);
        k_gmm<<<gmm_grid, 256, 0, stream>>>(adjb, h0h, h0l, dd, lmax, th0h, th0l, 4096);
        CellP g1{h0h, h0l, h1h, h1l, th0h, th0l, th1h, th1l,
                 G1TH, G1TL, BG1, nullptr, nullptr, nullptr, nullptr, nullptr, h1h, h1l, rbuf, zhh, zhl, 0};
        k_cellg2<256, false><<<dim3(512, 2), 256, 0, stream>>>(g1);
        k_gmm<<<gmm_grid, 256, 0, stream>>>(adjb, zhh, zhl, dd, lmax, tzh, tzl, 4096);
        CellP u1{h0h, h0l, zhh, zhl, th0h, th0l, tzh, tzl,
                 U1TH, U1TL, BU1, nullptr, nullptr, nullptr, nullptr, nullptr, nullptr, nullptr, rbuf, h1h, h1l, 0};
        k_cellu<256, false><<<NN, 256, 0, stream>>>(u1);
        if (t + 1 < TSEQ) {
            CellP g0n{h0h, h0l, th0h, th0l, nullptr, nullptr, nullptr, nullptr,
                      G0TH, G0TL, BG0, G0X, xsh, xsl, txh, txl, h0h, h0l, rbuf, zhh, zhl, (t + 1) * BB};
            FuseArgs fa{adjb, h1h, h1l, dd, lmax, th1h, th1l, g0n};
            k_fuse<<<1536, 256, 0, stream>>>(fa);
        }
    }

    k_conv<<<NN * BB / 256, 256, 0, stream>>>(h1h, h1l, cw, cb, out);
}

// Round 20
// 1695.898 us; speedup vs baseline: 1.2145x; 1.0247x over previous
//
#include <hip/hip_runtime.h>
#include <math.h>

#define NN 512
#define TSEQ 12
#define BB 64

typedef unsigned short u16;
typedef short s16x4 __attribute__((ext_vector_type(4)));
typedef short s16x8 __attribute__((ext_vector_type(8)));
typedef float f32x4 __attribute__((ext_vector_type(4)));

__device__ __forceinline__ float b2f(u16 h) { return __uint_as_float(((unsigned)h) << 16); }
__device__ __forceinline__ u16 f2b(float f) {
    unsigned u = __float_as_uint(f);
    return (u16)((u + 0x7FFFu + ((u >> 16) & 1u)) >> 16);
}

// ---------------- workspace layout (bytes) ----------------
constexpr size_t SZP    = (size_t)512 * 4096 * 2;   // one state plane (4 MB)
constexpr size_t B_ADJ  = 0;
constexpr size_t B_DD   = B_ADJ + 524288;
constexpr size_t B_NRM  = B_DD + 2048;
constexpr size_t B_LMAX = B_NRM + 2048;
constexpr size_t B_XSH  = B_LMAX + 256;
constexpr size_t B_XSL  = B_XSH + 786432;
constexpr size_t B_TXH  = B_XSL + 786432;
constexpr size_t B_TXL  = B_TXH + 786432;
constexpr size_t B_ST   = B_TXL + 786432;           // 12 planes
constexpr size_t B_RBUF = B_ST + 12 * SZP;
constexpr size_t B_G0TH = B_RBUF + 8388608;
constexpr size_t B_G0TL = B_G0TH + 16777216;
constexpr size_t B_U0TH = B_G0TL + 16777216;
constexpr size_t B_U0TL = B_U0TH + 8388608;
constexpr size_t B_G1TH = B_U0TL + 8388608;
constexpr size_t B_G1TL = B_G1TH + 33554432;
constexpr size_t B_U1TH = B_G1TL + 33554432;
constexpr size_t B_U1TL = B_U1TH + 16777216;
constexpr size_t B_BG0  = B_U1TL + 16777216;
constexpr size_t B_BU0  = B_BG0 + 262144;
constexpr size_t B_BG1  = B_BU0 + 131072;
constexpr size_t B_BU1  = B_BG1 + 262144;
constexpr size_t B_G0X  = B_BU1 + 131072;
constexpr size_t B_U0X  = B_G0X + 524288;
constexpr size_t WS_BYTES = B_U0X + 262144;         // ~205 MiB

// ---------------- setup kernels ----------------

__global__ void k_marker(float* out, float v) { out[threadIdx.x] = v; }

__global__ void k_norm(const float* __restrict__ E, float* __restrict__ nrm) {
    int n = blockIdx.x * blockDim.x + threadIdx.x;
    if (n < NN) {
        float s = 0.f;
        #pragma unroll
        for (int q = 0; q < 10; ++q) { float e = E[n * 10 + q]; s += e * e; }
        nrm[n] = sqrtf(s);
    }
}

__global__ __launch_bounds__(256) void k_adj(const float* __restrict__ E, const float* __restrict__ gn,
                                             const float* __restrict__ nrm, u16* __restrict__ adjb,
                                             float* __restrict__ dd) {
    __shared__ float En[10];
    __shared__ float red[256];
    int n = blockIdx.x, tid = threadIdx.x;
    if (tid < 10) En[tid] = E[n * 10 + tid];
    __syncthreads();
    float nn = nrm[n];
    float cnt = 0.f;
    for (int m = tid; m < NN; m += 256) {
        float dot = 0.f;
        #pragma unroll
        for (int q = 0; q < 10; ++q) dot += En[q] * E[m * 10 + q];
        float lg = dot / (nn * nrm[m]);
        lg = (lg + 1.f) * 0.5f;
        float g0 = gn[((size_t)n * NN + m) * 2 + 0];
        float g1 = gn[((size_t)n * NN + m) * 2 + 1];
        bool a = ((lg + g0) >= (1.f - lg + g1) && (m != n));
        adjb[(size_t)n * NN + m] = a ? 0x3F80 : 0;
        cnt += a ? 1.f : 0.f;
    }
    red[tid] = cnt;
    __syncthreads();
    for (int s = 128; s > 0; s >>= 1) { if (tid < s) red[tid] += red[tid + s]; __syncthreads(); }
    if (tid == 0) dd[n] = red[0];
}

__global__ void k_dmax(const float* __restrict__ dd, float* __restrict__ lmax) {
    __shared__ float red[512];
    int t = threadIdx.x;
    red[t] = dd[t];
    __syncthreads();
    for (int s = 256; s > 0; s >>= 1) { if (t < s) red[t] = fmaxf(red[t], red[t + s]); __syncthreads(); }
    if (t == 0) lmax[0] = red[0] + (red[0] > 0.f ? 1.f : 0.f);
}

__global__ __launch_bounds__(256) void k_xs_bf(const float* __restrict__ gts, u16* __restrict__ xh,
                                               u16* __restrict__ xl) {
    int idx = blockIdx.x * 256 + threadIdx.x;
    if (idx >= NN * TSEQ * BB) return;
    int n = idx / (TSEQ * BB);
    int rem = idx - n * (TSEQ * BB);
    int t = rem >> 6, b = rem & 63;
    float v = gts[((size_t)b * NN + n) * TSEQ + t];
    u16 hb = f2b(v);
    xh[idx] = hb;
    xl[idx] = f2b(v - b2f(hb));
}

// ---------------- embed v3 (round-16): Wp in LDS + fragment-major output ----------------
template <int K2, int O, bool SHIFT>
__global__ __launch_bounds__(256) void k_embed2(const float* __restrict__ E, const float* __restrict__ Wp,
                                                u16* __restrict__ oh, u16* __restrict__ ol) {
    constexpr int KR = SHIFT ? 130 : K2;
    constexpr int NKB = K2 / 32;
    __shared__ float WpL[10][32][33];
    __shared__ float eL[16][10];
    const int nc = blockIdx.x, kc = blockIdx.y, oc = blockIdx.z;
    const int tid = threadIdx.x;
    const int rb = kc * 32 + (SHIFT ? (kc >= 2 ? 2 : 1) : 0);
    const int ocol = oc * 32;
    const int n0 = nc * 16;

    for (int el = tid; el < 10 * 32 * 32; el += 256) {
        int d = el >> 10;
        int rem = el & 1023;
        int k = rem >> 5, o = rem & 31;
        WpL[d][k][o] = Wp[((size_t)d * KR + rb + k) * O + ocol + o];
    }
    if (tid < 160) eL[tid / 10][tid % 10] = E[(n0 + tid / 10) * 10 + tid % 10];
    __syncthreads();

    const int o2 = tid >> 3;
    const int kv = (tid & 7) * 4;
    const int o = ocol + o2;
    const int lane = ((kv >> 3) << 4) + (o & 15);
    const size_t fragbase =
        ((((size_t)0 * (O / 16) + (o >> 4)) * NKB + kc) * 64 + lane) * 8 + (kv & 7);
    const size_t nstride = (size_t)(O / 16) * NKB * 64 * 8;

    for (int ni = 0; ni < 16; ++ni) {
        float ev[10];
        #pragma unroll
        for (int d = 0; d < 10; ++d) ev[d] = eL[ni][d];
        u16 ph[4], pl[4];
        #pragma unroll
        for (int j = 0; j < 4; ++j) {
            float a = 0.f;
            #pragma unroll
            for (int d = 0; d < 10; ++d) a += ev[d] * WpL[d][kv + j][o2];
            u16 hb = f2b(a);
            ph[j] = hb;
            pl[j] = f2b(a - b2f(hb));
        }
        size_t off = fragbase + (size_t)(n0 + ni) * nstride;
        *(s16x4*)&oh[off] = *(s16x4*)ph;
        *(s16x4*)&ol[off] = *(s16x4*)pl;
    }
}

__global__ __launch_bounds__(256) void k_bias(const float* __restrict__ E, const float* __restrict__ gb0,
                                              const float* __restrict__ ub0, const float* __restrict__ gb1,
                                              const float* __restrict__ ub1, const float* __restrict__ gw0,
                                              const float* __restrict__ uw0,
                                              float* BG0, float* BU0, float* BG1, float* BU1,
                                              float* G0X, float* U0X) {
    __shared__ float e[10];
    int n = blockIdx.x, tid = threadIdx.x;
    if (tid < 10) e[tid] = E[n * 10 + tid];
    __syncthreads();
    if (tid < 128) {
        int o = tid;
        float a0 = 0, a1 = 0, a2 = 0, a3 = 0;
        #pragma unroll
        for (int d = 0; d < 10; ++d) {
            a0 += e[d] * gb0[d * 128 + o];
            a1 += e[d] * gb1[d * 128 + o];
            a2 += e[d] * gw0[((size_t)d * 130 + 0) * 128 + o];
            a3 += e[d] * gw0[((size_t)d * 130 + 65) * 128 + o];
        }
        BG0[n * 128 + o] = a0; BG1[n * 128 + o] = a1;
        G0X[n * 256 + o] = a2; G0X[n * 256 + 128 + o] = a3;
    } else if (tid < 192) {
        int o = tid - 128;
        float a0 = 0, a1 = 0, a2 = 0, a3 = 0;
        #pragma unroll
        for (int d = 0; d < 10; ++d) {
            a0 += e[d] * ub0[d * 64 + o];
            a1 += e[d] * ub1[d * 64 + o];
            a2 += e[d] * uw0[((size_t)d * 130 + 0) * 64 + o];
            a3 += e[d] * uw0[((size_t)d * 130 + 65) * 64 + o];
        }
        BU0[n * 64 + o] = a0; BU1[n * 64 + o] = a1;
        U0X[n * 128 + o] = a2; U0X[n * 128 + 64 + o] = a3;
    }
}

// ---------------- gmm shared + device body (round-17 verified) ----------------
struct GmmS {
    u16 As[2][64][72];
    u16 Bsh[2][2][64][32];
    u16 Bsl[2][2][64][32];
};

__device__ __forceinline__ void d_gmm(int by, int bx_, int tid,
                                      const u16* __restrict__ A, const u16* __restrict__ Bh,
                                      const u16* __restrict__ Bl, const float* __restrict__ dd,
                                      const float* __restrict__ lmax,
                                      u16* __restrict__ Ch, u16* __restrict__ Cl, int N, GmmS& S) {
    const int w = tid >> 6, l = tid & 63, lr = l & 15, lg = l >> 4;
    const int bm = by * 64, bn = bx_ * 64;
    const int am = tid >> 2, ak = (tid & 3) * 16;
    const int bk = tid >> 3, bn8 = (tid & 7) * 8;
    const int bx = (tid & 7) & 3;
    const int col = ((bk >> 3) ^ bx) * 8 + (bk & 7);
    f32x4 acc[4];
    #pragma unroll
    for (int a = 0; a < 4; ++a) acc[a] = (f32x4){0.f, 0.f, 0.f, 0.f};

    const int nl = w * 16 + lr;
    const int cc = (lg ^ ((nl >> 3) & 3)) * 8;
    const size_t arow = (size_t)(bm + am) * 512;

    s16x8 rA0, rA1, rBh[2], rBl[2];
    rA0 = *(const s16x8*)&A[arow + 0 + ak];
    rA1 = *(const s16x8*)&A[arow + 0 + ak + 8];
    #pragma unroll
    for (int hh = 0; hh < 2; ++hh) {
        rBh[hh] = *(const s16x8*)&Bh[(size_t)(0 + hh * 32 + bk) * N + bn + bn8];
        rBl[hh] = *(const s16x8*)&Bl[(size_t)(0 + hh * 32 + bk) * N + bn + bn8];
    }
    *(s16x8*)&S.As[0][am][ak]     = rA0;
    *(s16x8*)&S.As[0][am][ak + 8] = rA1;
    #pragma unroll
    for (int hh = 0; hh < 2; ++hh) {
        #pragma unroll
        for (int q = 0; q < 8; ++q) {
            S.Bsh[0][hh][bn8 + q][col] = ((const u16*)&rBh[hh])[q];
            S.Bsl[0][hh][bn8 + q][col] = ((const u16*)&rBl[hh])[q];
        }
    }
    __syncthreads();

    for (int k0 = 0; k0 < 512; k0 += 64) {
        const int cur = (k0 >> 6) & 1;
        const bool more = (k0 + 64 < 512);
        if (more) {
            rA0 = *(const s16x8*)&A[arow + k0 + 64 + ak];
            rA1 = *(const s16x8*)&A[arow + k0 + 64 + ak + 8];
            #pragma unroll
            for (int hh = 0; hh < 2; ++hh) {
                rBh[hh] = *(const s16x8*)&Bh[(size_t)(k0 + 64 + hh * 32 + bk) * N + bn + bn8];
                rBl[hh] = *(const s16x8*)&Bl[(size_t)(k0 + 64 + hh * 32 + bk) * N + bn + bn8];
            }
        }
        #pragma unroll
        for (int hh = 0; hh < 2; ++hh) {
            s16x8 bfh = *(const s16x8*)&S.Bsh[cur][hh][nl][cc];
            s16x8 bfl = *(const s16x8*)&S.Bsl[cur][hh][nl][cc];
            #pragma unroll
            for (int mf = 0; mf < 4; ++mf) {
                s16x8 afr = *(const s16x8*)&S.As[cur][mf * 16 + lr][hh * 32 + lg * 8];
                acc[mf] = __builtin_amdgcn_mfma_f32_16x16x32_bf16(afr, bfh, acc[mf], 0, 0, 0);
                acc[mf] = __builtin_amdgcn_mfma_f32_16x16x32_bf16(afr, bfl, acc[mf], 0, 0, 0);
            }
        }
        if (more) {
            const int nxt = cur ^ 1;
            *(s16x8*)&S.As[nxt][am][ak]     = rA0;
            *(s16x8*)&S.As[nxt][am][ak + 8] = rA1;
            #pragma unroll
            for (int hh = 0; hh < 2; ++hh) {
                #pragma unroll
                for (int q = 0; q < 8; ++q) {
                    S.Bsh[nxt][hh][bn8 + q][col] = ((const u16*)&rBh[hh])[q];
                    S.Bsl[nxt][hh][bn8 + q][col] = ((const u16*)&rBl[hh])[q];
                }
            }
        }
        __syncthreads();
    }
    const float lm = lmax[0], alpha = -2.f / lm;
    const int colg = bn + w * 16 + lr;
    #pragma unroll
    for (int mf = 0; mf < 4; ++mf) {
        #pragma unroll
        for (int i = 0; i < 4; ++i) {
            int rowg = bm + mf * 16 + lg * 4 + i;
            size_t off = (size_t)rowg * N + colg;
            float hval = b2f(Bh[off]) + b2f(Bl[off]);
            float beta = 2.f * dd[rowg] / lm - 1.f;
            float v = alpha * acc[mf][i] + beta * hval;
            u16 hb = f2b(v);
            Ch[off] = hb;
            Cl[off] = f2b(v - b2f(hb));
        }
    }
}

__global__ __launch_bounds__(256) void k_gmm(const u16* __restrict__ A, const u16* __restrict__ Bh,
                                             const u16* __restrict__ Bl, const float* __restrict__ dd,
                                             const float* __restrict__ lmax,
                                             u16* __restrict__ Ch, u16* __restrict__ Cl, int N) {
    __shared__ GmmS S;
    d_gmm(blockIdx.y, blockIdx.x, threadIdx.x, A, Bh, Bl, dd, lmax, Ch, Cl, N, S);
}

// ---------------- split-precision MFMA cells ----------------
struct CellP {
    const u16 *s0h, *s0l, *s1h, *s1l, *s2h, *s2l, *s3h, *s3l;
    const u16 *Wh, *Wl;
    const float *bias, *wx;
    const u16 *xsh, *xsl, *txh, *txl;
    const u16 *hph, *hpl;
    float* rbuf;
    u16 *oh, *ol;
    int xoff;
};

// ROUND 20: UPDATE cell split by batch-half — block = (node, mhalf), 1024 blocks (4/CU).
// Each wave: 1 m-fragment x 2 n-fragments (was 2x2). Per-output K-loop/MFMA chain and
// weight fragments identical to round 19 -> bit-identical; weights streamed 2x (L2/L3-hit).
template <int K2, bool RANK1>
__device__ __forceinline__ void d_cellu2(int n, int mhalf, int tid, const CellP& p) {
    constexpr int NKB = K2 / 32;
    const int w = tid >> 6, l = tid & 63, lr = l & 15, lg = l >> 4;
    const int mf = mhalf * 2 + (w >> 1);     // m-fragment 0..3
    const int nbase = (w & 1) * 2;
    f32x4 acc[2];
    #pragma unroll
    for (int c = 0; c < 2; ++c) acc[c] = (f32x4){0.f, 0.f, 0.f, 0.f};
    const size_t nb = (size_t)n * 4096;

    #pragma unroll
    for (int kb = 0; kb < NKB; ++kb) {
        const int sg = kb >> 1;
        const u16* sh = sg == 0 ? p.s0h : sg == 1 ? p.s1h : sg == 2 ? p.s2h : p.s3h;
        const u16* sl = sg == 0 ? p.s0l : sg == 1 ? p.s1l : sg == 2 ? p.s2l : p.s3l;
        const int koff = (kb & 1) * 32 + lg * 8;
        s16x8 bfh[2], bfl[2];
        #pragma unroll
        for (int nf = 0; nf < 2; ++nf) {
            size_t wof = ((((size_t)n * 4 + (nbase + nf)) * NKB + kb) * 64 + l) * 8;
            bfh[nf] = *(const s16x8*)&p.Wh[wof];
            bfl[nf] = *(const s16x8*)&p.Wl[wof];
        }
        int b = mf * 16 + lr;
        s16x8 ah = *(const s16x8*)&sh[nb + b * 64 + koff];
        s16x8 al = *(const s16x8*)&sl[nb + b * 64 + koff];
        #pragma unroll
        for (int nf = 0; nf < 2; ++nf) {
            acc[nf] = __builtin_amdgcn_mfma_f32_16x16x32_bf16(ah, bfh[nf], acc[nf], 0, 0, 0);
            acc[nf] = __builtin_amdgcn_mfma_f32_16x16x32_bf16(ah, bfl[nf], acc[nf], 0, 0, 0);
            acc[nf] = __builtin_amdgcn_mfma_f32_16x16x32_bf16(al, bfh[nf], acc[nf], 0, 0, 0);
        }
    }

    const float* wxn = RANK1 ? (p.wx + (size_t)n * 2 * 64) : p.wx;
    #pragma unroll
    for (int i = 0; i < 4; ++i) {
        int b = mf * 16 + lg * 4 + i;
        float xf = 0.f, txf = 0.f;
        if (RANK1) {
            int idx = n * 768 + p.xoff + b;
            xf = b2f(p.xsh[idx]) + b2f(p.xsl[idx]);
            txf = b2f(p.txh[idx]) + b2f(p.txl[idx]);
        }
        #pragma unroll
        for (int nf = 0; nf < 2; ++nf) {
            int o = (nbase + nf) * 16 + lr;
            float s = acc[nf][i] + p.bias[(size_t)n * 64 + o];
            if (RANK1) s += xf * wxn[o] + txf * wxn[64 + o];
            size_t bo = nb + (size_t)b * 64;
            float hc = tanhf(s);
            float rv = p.rbuf[bo + o];
            float hp = b2f(p.oh[bo + o]) + b2f(p.ol[bo + o]);
            float hn = rv * hp + (1.f - rv) * hc;
            u16 hb = f2b(hn);
            p.oh[bo + o] = hb;
            p.ol[bo + o] = f2b(hn - b2f(hb));
        }
    }
}
template <int K2, bool RANK1>
__global__ __launch_bounds__(256) void k_cellu2(CellP p) {
    d_cellu2<K2, RANK1>(blockIdx.x, blockIdx.y, threadIdx.x, p);
}

// GATE cell split by o-half (round-19 verified)
template <int K2, bool RANK1>
__device__ __forceinline__ void d_cellg2(int n, int ohalf, int tid, const CellP& p) {
    constexpr int NKB = K2 / 32;
    const int w = tid >> 6, l = tid & 63, lr = l & 15, lg = l >> 4;
    const int mbase = (w >> 1) * 2;
    const int nbase = (w & 1) * 2;
    f32x4 acc[2][2];
    #pragma unroll
    for (int a = 0; a < 2; ++a)
        #pragma unroll
        for (int c = 0; c < 2; ++c) acc[a][c] = (f32x4){0.f, 0.f, 0.f, 0.f};
    const size_t nb = (size_t)n * 4096;

    #pragma unroll
    for (int kb = 0; kb < NKB; ++kb) {
        const int sg = kb >> 1;
        const u16* sh = sg == 0 ? p.s0h : sg == 1 ? p.s1h : sg == 2 ? p.s2h : p.s3h;
        const u16* sl = sg == 0 ? p.s0l : sg == 1 ? p.s1l : sg == 2 ? p.s2l : p.s3l;
        const int koff = (kb & 1) * 32 + lg * 8;
        s16x8 bfh[2], bfl[2];
        #pragma unroll
        for (int nf = 0; nf < 2; ++nf) {
            size_t wof = ((((size_t)n * 8 + ohalf * 4 + nbase + nf) * NKB + kb) * 64 + l) * 8;
            bfh[nf] = *(const s16x8*)&p.Wh[wof];
            bfl[nf] = *(const s16x8*)&p.Wl[wof];
        }
        #pragma unroll
        for (int mf = 0; mf < 2; ++mf) {
            int b = (mbase + mf) * 16 + lr;
            s16x8 ah = *(const s16x8*)&sh[nb + b * 64 + koff];
            s16x8 al = *(const s16x8*)&sl[nb + b * 64 + koff];
            #pragma unroll
            for (int nf = 0; nf < 2; ++nf) {
                acc[mf][nf] = __builtin_amdgcn_mfma_f32_16x16x32_bf16(ah, bfh[nf], acc[mf][nf], 0, 0, 0);
                acc[mf][nf] = __builtin_amdgcn_mfma_f32_16x16x32_bf16(ah, bfl[nf], acc[mf][nf], 0, 0, 0);
                acc[mf][nf] = __builtin_amdgcn_mfma_f32_16x16x32_bf16(al, bfh[nf], acc[mf][nf], 0, 0, 0);
            }
        }
    }

    const float* wxn = RANK1 ? (p.wx + (size_t)n * 2 * 128) : p.wx;
    #pragma unroll
    for (int mf = 0; mf < 2; ++mf) {
        #pragma unroll
        for (int i = 0; i < 4; ++i) {
            int b = (mbase + mf) * 16 + lg * 4 + i;
            float xf = 0.f, txf = 0.f;
            if (RANK1) {
                int idx = n * 768 + p.xoff + b;
                xf = b2f(p.xsh[idx]) + b2f(p.xsl[idx]);
                txf = b2f(p.txh[idx]) + b2f(p.txl[idx]);
            }
            #pragma unroll
            for (int nf = 0; nf < 2; ++nf) {
                int o = ohalf * 64 + (nbase + nf) * 16 + lr;
                float s = acc[mf][nf][i] + p.bias[(size_t)n * 128 + o];
                if (RANK1) s += xf * wxn[o] + txf * wxn[128 + o];
                size_t bo = nb + (size_t)b * 64;
                float v = 1.f / (1.f + expf(-s));
                if (o < 64) {
                    float hp = b2f(p.hph[bo + o]) + b2f(p.hpl[bo + o]);
                    float zh = v * hp;
                    u16 hb = f2b(zh);
                    p.oh[bo + o] = hb;
                    p.ol[bo + o] = f2b(zh - b2f(hb));
                } else {
                    p.rbuf[bo + (o - 64)] = v;
                }
            }
        }
    }
}
template <int K2, bool RANK1>
__global__ __launch_bounds__(256) void k_cellg2(CellP p) {
    d_cellg2<K2, RANK1>(blockIdx.x, blockIdx.y, threadIdx.x, p);
}

// ---------------- fused (gmm h1->th1) + (next step's split g0 cell) ----------------
struct FuseArgs {
    const u16* adjb; const u16 *h1h, *h1l; const float *dd, *lmax;
    u16 *th1h, *th1l;
    CellP cell;
};
__global__ __launch_bounds__(256) void k_fuse(FuseArgs a) {
    __shared__ GmmS S;
    const int bid = blockIdx.x;
    if (bid < 512) {
        d_gmm(bid >> 6, bid & 63, threadIdx.x, a.adjb, a.h1h, a.h1l, a.dd, a.lmax,
              a.th1h, a.th1l, 4096, S);
    } else {
        const int cb = bid - 512;
        d_cellg2<128, true>(cb >> 1, cb & 1, threadIdx.x, a.cell);
    }
}

// ---------------- end conv ----------------
__global__ __launch_bounds__(256) void k_conv(const u16* __restrict__ hh, const u16* __restrict__ hl,
                                              const float* __restrict__ cw, const float* __restrict__ cb,
                                              float* __restrict__ out) {
    int idx = blockIdx.x * 256 + threadIdx.x;
    int n = idx >> 6, b = idx & 63;
    float hv[64];
    #pragma unroll
    for (int q = 0; q < 8; ++q) {
        s16x8 vh = *(const s16x8*)&hh[(size_t)n * 4096 + b * 64 + q * 8];
        s16x8 vl = *(const s16x8*)&hl[(size_t)n * 4096 + b * 64 + q * 8];
        #pragma unroll
        for (int j = 0; j < 8; ++j) hv[q * 8 + j] = b2f((u16)vh[j]) + b2f((u16)vl[j]);
    }
    #pragma unroll
    for (int t = 0; t < TSEQ; ++t) {
        float s = cb[t];
        #pragma unroll
        for (int j = 0; j < 64; ++j) s += hv[j] * cw[t * 64 + j];
        out[((size_t)b * TSEQ + t) * NN + n] = s;
    }
}

// ---------------- launch ----------------
extern "C" void kernel_launch(void* const* d_in, const int* in_sizes, int n_in,
                              void* d_out, int out_size, void* d_ws, size_t ws_size,
                              hipStream_t stream) {
    const float* gts = (const float*)d_in[0];
    const float* gn  = (const float*)d_in[1];
    const float* E   = (const float*)d_in[2];
    const float* gw0 = (const float*)d_in[3];
    const float* gb0 = (const float*)d_in[4];
    const float* uw0 = (const float*)d_in[5];
    const float* ub0 = (const float*)d_in[6];
    const float* gw1 = (const float*)d_in[7];
    const float* gb1 = (const float*)d_in[8];
    const float* uw1 = (const float*)d_in[9];
    const float* ub1 = (const float*)d_in[10];
    const float* cw  = (const float*)d_in[11];
    const float* cb  = (const float*)d_in[12];
    float* out = (float*)d_out;
    char* ws = (char*)d_ws;

    if (ws_size < WS_BYTES) {
        k_marker<<<1, 64, 0, stream>>>(out, (float)(ws_size >> 20));
        return;
    }

    u16* adjb = (u16*)(ws + B_ADJ);
    float* dd = (float*)(ws + B_DD);
    float* nrm = (float*)(ws + B_NRM);
    float* lmax = (float*)(ws + B_LMAX);
    u16* xsh = (u16*)(ws + B_XSH);
    u16* xsl = (u16*)(ws + B_XSL);
    u16* txh = (u16*)(ws + B_TXH);
    u16* txl = (u16*)(ws + B_TXL);
    u16* h0h  = (u16*)(ws + B_ST + 0 * SZP);
    u16* h0l  = (u16*)(ws + B_ST + 1 * SZP);
    u16* h1h  = (u16*)(ws + B_ST + 2 * SZP);
    u16* h1l  = (u16*)(ws + B_ST + 3 * SZP);
    u16* th0h = (u16*)(ws + B_ST + 4 * SZP);
    u16* th0l = (u16*)(ws + B_ST + 5 * SZP);
    u16* th1h = (u16*)(ws + B_ST + 6 * SZP);
    u16* th1l = (u16*)(ws + B_ST + 7 * SZP);
    u16* zhh  = (u16*)(ws + B_ST + 8 * SZP);
    u16* zhl  = (u16*)(ws + B_ST + 9 * SZP);
    u16* tzh  = (u16*)(ws + B_ST + 10 * SZP);
    u16* tzl  = (u16*)(ws + B_ST + 11 * SZP);
    float* rbuf = (float*)(ws + B_RBUF);
    u16* G0TH = (u16*)(ws + B_G0TH);
    u16* G0TL = (u16*)(ws + B_G0TL);
    u16* U0TH = (u16*)(ws + B_U0TH);
    u16* U0TL = (u16*)(ws + B_U0TL);
    u16* G1TH = (u16*)(ws + B_G1TH);
    u16* G1TL = (u16*)(ws + B_G1TL);
    u16* U1TH = (u16*)(ws + B_U1TH);
    u16* U1TL = (u16*)(ws + B_U1TL);
    float* BG0 = (float*)(ws + B_BG0);
    float* BU0 = (float*)(ws + B_BU0);
    float* BG1 = (float*)(ws + B_BG1);
    float* BU1 = (float*)(ws + B_BU1);
    float* G0X = (float*)(ws + B_G0X);
    float* U0X = (float*)(ws + B_U0X);

    // REPLAY DETERMINISM: zero the ENTIRE used workspace every call (round-8 proven).
    hipMemsetAsync(ws, 0, WS_BYTES, stream);

    k_norm<<<2, 256, 0, stream>>>(E, nrm);
    k_adj<<<NN, 256, 0, stream>>>(E, gn, nrm, adjb, dd);
    k_dmax<<<1, 512, 0, stream>>>(dd, lmax);

    k_xs_bf<<<(NN * TSEQ * BB + 255) / 256, 256, 0, stream>>>(gts, xsh, xsl);
    k_gmm<<<dim3(TSEQ * BB / 64, 8), 256, 0, stream>>>(adjb, xsh, xsl, dd, lmax, txh, txl, TSEQ * BB);

    k_embed2<128, 128, true><<<dim3(32, 4, 4), 256, 0, stream>>>(E, gw0, G0TH, G0TL);
    k_embed2<128, 64, true><<<dim3(32, 4, 2), 256, 0, stream>>>(E, uw0, U0TH, U0TL);
    k_embed2<256, 128, false><<<dim3(32, 8, 4), 256, 0, stream>>>(E, gw1, G1TH, G1TL);
    k_embed2<256, 64, false><<<dim3(32, 8, 2), 256, 0, stream>>>(E, uw1, U1TH, U1TL);
    k_bias<<<512, 256, 0, stream>>>(E, gb0, ub0, gb1, ub1, gw0, uw0,
                                    BG0, BU0, BG1, BU1, G0X, U0X);

    const dim3 gmm_grid(BB * 64 / 64, 8);
    for (int t = 0; t < TSEQ; ++t) {
        int xoff = t * BB;
        if (t == 0) {
            CellP g0{h0h, h0l, th0h, th0l, nullptr, nullptr, nullptr, nullptr,
                     G0TH, G0TL, BG0, G0X, xsh, xsl, txh, txl, h0h, h0l, rbuf, zhh, zhl, xoff};
            k_cellg2<128, true><<<dim3(512, 2), 256, 0, stream>>>(g0);
        }
        k_gmm<<<gmm_grid, 256, 0, stream>>>(adjb, zhh, zhl, dd, lmax, tzh, tzl, 4096);
        CellP u0{zhh, zhl, tzh, tzl, nullptr, nullptr, nullptr, nullptr,
                 U0TH, U0TL, BU0, U0X, xsh, xsl, txh, txl, nullptr, nullptr, rbuf, h0h, h0l, xoff};
        k_cellu2<128, true><<<dim3(512, 2), 256, 0, stream>>>(u0);
        k_gmm<<<gmm_grid, 256, 0, stream>>>(adjb, h0h, h0l, dd, lmax, th0h, th0l, 4096);
        CellP g1{h0h, h0l, h1h, h1l, th0h, th0l, th1h, th1l,
                 G1TH, G1TL, BG1, nullptr, nullptr, nullptr, nullptr, nullptr, h1h, h1l, rbuf, zhh, zhl, 0};
        k_cellg2<256, false><<<dim3(512, 2), 256, 0, stream>>>(g1);
        k_gmm<<<gmm_grid, 256, 0, stream>>>(adjb, zhh, zhl, dd, lmax, tzh, tzl, 4096);
        CellP u1{h0h, h0l, zhh, zhl, th0h, th0l, tzh, tzl,
                 U1TH, U1TL, BU1, nullptr, nullptr, nullptr, nullptr, nullptr, nullptr, nullptr, rbuf, h1h, h1l, 0};
        k_cellu2<256, false><<<dim3(512, 2), 256, 0, stream>>>(u1);
        if (t + 1 < TSEQ) {
            CellP g0n{h0h, h0l, th0h, th0l, nullptr, nullptr, nullptr, nullptr,
                      G0TH, G0TL, BG0, G0X, xsh, xsl, txh, txl, h0h, h0l, rbuf, zhh, zhl, (t + 1) * BB};
            FuseArgs fa{adjb, h1h, h1l, dd, lmax, th1h, th1l, g0n};
            k_fuse<<<1536, 256, 0, stream>>>(fa);
        }
    }

    k_conv<<<NN * BB / 256, 256, 0, stream>>>(h1h, h1l, cw, cb, out);
}